// Round 1
// baseline (565.229 us; speedup 1.0000x reference)
//
#include <hip/hip_runtime.h>
#include <math.h>

#define BB 32
#define LL 1024
#define DIMM 64
#define DINN 256
#define NHEADS 4
#define DSTATE 16
#define DINPROJ 548
#define EPSF 1e-5f

// ---------------- K1: RMSNorm + in_proj + softplus(dt) ----------------
// grid (9 col-tiles, 1024 row-tiles), block 256
__global__ __launch_bounds__(256) void k1_inproj(
        const float* __restrict__ x, const float* __restrict__ W,
        const float* __restrict__ bnw, const float* __restrict__ dt_bias,
        float* __restrict__ zxb) {
    __shared__ float u[32][68];
    __shared__ float rstd[32];
    const int t = threadIdx.x;
    const int m0 = blockIdx.y * 32;          // global row (b*1024+l)
    const int ct = blockIdx.x;               // col tile (64 cols)

    // load 32 rows x 64 cols (contiguous 2048 floats)
    const float* xrow = x + (size_t)m0 * 64;
    #pragma unroll
    for (int i = 0; i < 2; ++i) {
        int idx = t + i * 256;               // float4 index
        float4 v = ((const float4*)xrow)[idx];
        int row = idx >> 4, col4 = (idx & 15) * 4;
        *(float4*)&u[row][col4] = v;
    }
    __syncthreads();
    if (t < 32) {
        float s = 0.f;
        #pragma unroll 8
        for (int k = 0; k < 64; ++k) { float v = u[t][k]; s = fmaf(v, v, s); }
        rstd[t] = rsqrtf(s * (1.f / 64.f) + EPSF);
    }
    __syncthreads();
    #pragma unroll
    for (int i = 0; i < 8; ++i) {
        int idx = t + i * 256; int row = idx >> 6, col = idx & 63;
        u[row][col] *= rstd[row] * bnw[col];
    }
    __syncthreads();

    const int tc = t & 63, tr = t >> 6;
    const int c = ct * 64 + tc;
    const bool valid = (c < DINPROJ);
    const float* wrow = W + (size_t)(valid ? c : 0) * 64;

    float acc[8] = {0.f,0.f,0.f,0.f,0.f,0.f,0.f,0.f};
    for (int kc = 0; kc < 16; ++kc) {
        float4 w4 = *(const float4*)&wrow[kc * 4];
        #pragma unroll
        for (int r = 0; r < 8; ++r) {
            float4 a4 = *(const float4*)&u[tr * 8 + r][kc * 4];
            acc[r] = fmaf(a4.x, w4.x, acc[r]);
            acc[r] = fmaf(a4.y, w4.y, acc[r]);
            acc[r] = fmaf(a4.z, w4.z, acc[r]);
            acc[r] = fmaf(a4.w, w4.w, acc[r]);
        }
    }
    if (valid) {
        float* orow = zxb + (size_t)m0 * DINPROJ + c;
        #pragma unroll
        for (int r = 0; r < 8; ++r) {
            float v = acc[r];
            if (c >= 544) {  // dt columns: softplus(v + dt_bias[h])
                v += dt_bias[c - 544];
                v = fmaxf(v, 0.f) + log1pf(expf(-fabsf(v)));
            }
            orow[(size_t)(tr * 8 + r) * DINPROJ] = v;
        }
    }
}

// ---------------- K3: conv+SiLU fused + sequential scan ----------------
// grid 128 = (b,h), block 256: p = t>>2 (0..63), q = t&3 owns n in [4q,4q+4)
__global__ __launch_bounds__(256) void k3_scan(
        const float* __restrict__ zxb, const float* __restrict__ conv_w,
        const float* __restrict__ conv_b, const float* __restrict__ A_log,
        const float* __restrict__ Dp, float* __restrict__ y) {
    const int b = blockIdx.x >> 2;
    const int h = blockIdx.x & 3;
    const int t = threadIdx.x;

    __shared__ float rawx[35][64];
    __shared__ float rawbc[35][32];
    __shared__ float xt[32][64];
    __shared__ float Bt[32][16];
    __shared__ float Ct[32][16];
    __shared__ float dtt[32];
    __shared__ float dAt[32];
    __shared__ float yt[32][64];

    const float A  = -expf(A_log[h]);
    const float Dh = Dp[h];

    const int jx  = t & 63;                 // x-channel within head
    const int cx  = h * 64 + jx;            // conv channel 0..255
    const float4 cwx = *(const float4*)&conv_w[cx * 4];
    const float  cbx = conv_b[cx];
    const int jbc = t & 31;                 // B/C channel 0..31
    const int cbc = 256 + jbc;
    const float4 cwb = *(const float4*)&conv_w[cbc * 4];
    const float  cbb = conv_b[cbc];

    const float* zb = zxb + (size_t)b * LL * DINPROJ;
    const int p = t >> 2, q = t & 3, n0 = q * 4;
    float4 st = {0.f, 0.f, 0.f, 0.f};

    for (int it = 0; it < 32; ++it) {
        const int l0 = it * 32;
        // stage raw rows l0-3 .. l0+31
        for (int i = t; i < 35 * 64; i += 256) {
            int r = i >> 6, j = i & 63;
            int l = l0 - 3 + r;
            rawx[r][j] = (l >= 0) ? zb[(size_t)l * DINPROJ + 256 + h * 64 + j] : 0.f;
        }
        for (int i = t; i < 35 * 32; i += 256) {
            int r = i >> 5, j = i & 31;
            int l = l0 - 3 + r;
            rawbc[r][j] = (l >= 0) ? zb[(size_t)l * DINPROJ + 512 + j] : 0.f;
        }
        if (t < 32) {
            float v = zb[(size_t)(l0 + t) * DINPROJ + 544 + h]; // softplus'ed dt
            dtt[t] = v;
            dAt[t] = expf(v * A);
        }
        __syncthreads();
        // depthwise conv (k=4) + SiLU
        #pragma unroll
        for (int i = 0; i < 8; ++i) {
            int s = (t + i * 256) >> 6;
            float v = cbx + rawx[s][jx] * cwx.x + rawx[s + 1][jx] * cwx.y
                          + rawx[s + 2][jx] * cwx.z + rawx[s + 3][jx] * cwx.w;
            xt[s][jx] = v / (1.f + expf(-v));
        }
        #pragma unroll
        for (int i = 0; i < 4; ++i) {
            int s = (t + i * 256) >> 5;
            float v = cbb + rawbc[s][jbc] * cwb.x + rawbc[s + 1][jbc] * cwb.y
                          + rawbc[s + 2][jbc] * cwb.z + rawbc[s + 3][jbc] * cwb.w;
            v = v / (1.f + expf(-v));
            if (jbc < 16) Bt[s][jbc] = v; else Ct[s][jbc - 16] = v;
        }
        __syncthreads();
        // 32 sequential scan steps
        #pragma unroll 4
        for (int s = 0; s < 32; ++s) {
            float xv = xt[s][p];
            float4 Bv = *(const float4*)&Bt[s][n0];
            float4 Cv = *(const float4*)&Ct[s][n0];
            float dt = dtt[s], dA = dAt[s];
            float dtx = dt * xv;
            st.x = fmaf(st.x, dA, dtx * Bv.x);
            st.y = fmaf(st.y, dA, dtx * Bv.y);
            st.z = fmaf(st.z, dA, dtx * Bv.z);
            st.w = fmaf(st.w, dA, dtx * Bv.w);
            float yp = st.x * Cv.x + st.y * Cv.y + st.z * Cv.z + st.w * Cv.w;
            yp += __shfl_xor(yp, 1);
            yp += __shfl_xor(yp, 2);
            if (q == 0) yt[s][p] = fmaf(Dh, xv, yp);
        }
        __syncthreads();
        // flush y tile (layout (b,l,256))
        float* yb = y + ((size_t)b * LL + l0) * DINN + h * 64;
        #pragma unroll
        for (int i = 0; i < 8; ++i) {
            int idx = t + i * 256; int s = idx >> 6, j = idx & 63;
            yb[(size_t)s * DINN + j] = yt[s][j];
        }
        __syncthreads();
    }
}

// ---------------- K4: gate + RMSNorm + out_proj + residuals ----------------
// grid 1024 row-tiles, block 256
__global__ __launch_bounds__(256) void k4_out(
        const float* __restrict__ y, const float* __restrict__ zxb,
        const float* __restrict__ ngw, const float* __restrict__ Wout,
        const float* __restrict__ x, float* __restrict__ out) {
    __shared__ float g[32][260];
    __shared__ float rstd[32];
    const int t = threadIdx.x;
    const int m0 = blockIdx.x * 32;
    const float* yb = y + (size_t)m0 * DINN;
    const float* zb = zxb + (size_t)m0 * DINPROJ;

    #pragma unroll
    for (int i = 0; i < 8; ++i) {
        int idx = t + i * 256;               // float4 index over 2048
        int row = idx >> 6, col4 = (idx & 63) * 4;
        float4 yv = *(const float4*)&yb[(size_t)row * DINN + col4];
        float4 zv = *(const float4*)&zb[(size_t)row * DINPROJ + col4];
        float4 gv;
        gv.x = yv.x * zv.x / (1.f + expf(-zv.x));
        gv.y = yv.y * zv.y / (1.f + expf(-zv.y));
        gv.z = yv.z * zv.z / (1.f + expf(-zv.z));
        gv.w = yv.w * zv.w / (1.f + expf(-zv.w));
        *(float4*)&g[row][col4] = gv;
    }
    __syncthreads();
    {
        int row = t >> 3, part = t & 7;
        float s = 0.f;
        #pragma unroll 8
        for (int j = 0; j < 32; ++j) { float v = g[row][part * 32 + j]; s = fmaf(v, v, s); }
        s += __shfl_xor(s, 1); s += __shfl_xor(s, 2); s += __shfl_xor(s, 4);
        if (part == 0) rstd[row] = rsqrtf(s * (1.f / 256.f) + EPSF);
    }
    __syncthreads();
    #pragma unroll
    for (int i = 0; i < 8; ++i) {
        int idx = t + i * 256;
        int row = idx >> 6, col4 = (idx & 63) * 4;
        float4 n4 = *(const float4*)&ngw[col4];
        float4 gv = *(const float4*)&g[row][col4];
        float rs = rstd[row];
        gv.x *= rs * n4.x; gv.y *= rs * n4.y; gv.z *= rs * n4.z; gv.w *= rs * n4.w;
        *(float4*)&g[row][col4] = gv;
    }
    __syncthreads();

    const int tc = t & 63, tr = t >> 6;      // output dim d = tc
    const float* wrow = Wout + (size_t)tc * DINN;
    float acc[8] = {0.f,0.f,0.f,0.f,0.f,0.f,0.f,0.f};
    for (int kc = 0; kc < 64; ++kc) {
        float4 w4 = *(const float4*)&wrow[kc * 4];
        #pragma unroll
        for (int r = 0; r < 8; ++r) {
            float4 a4 = *(const float4*)&g[tr * 8 + r][kc * 4];
            acc[r] = fmaf(a4.x, w4.x, acc[r]);
            acc[r] = fmaf(a4.y, w4.y, acc[r]);
            acc[r] = fmaf(a4.z, w4.z, acc[r]);
            acc[r] = fmaf(a4.w, w4.w, acc[r]);
        }
    }
    #pragma unroll
    for (int r = 0; r < 8; ++r) {
        size_t row = (size_t)m0 + tr * 8 + r;      // b*1024+l
        size_t oidx = row * 64 + tc;               // flat (B,T)
        out[oidx] = acc[r] + 2.f * x[oidx];        // hidden + batch + x
    }
}

extern "C" void kernel_launch(void* const* d_in, const int* in_sizes, int n_in,
                              void* d_out, int out_size, void* d_ws, size_t ws_size,
                              hipStream_t stream) {
    const float* x          = (const float*)d_in[0];
    const float* in_proj_w  = (const float*)d_in[1];
    const float* conv_w     = (const float*)d_in[2];
    const float* conv_b     = (const float*)d_in[3];
    const float* dt_bias    = (const float*)d_in[4];
    const float* A_log      = (const float*)d_in[5];
    const float* D          = (const float*)d_in[6];
    const float* norm_gate  = (const float*)d_in[7];
    const float* out_proj_w = (const float*)d_in[8];
    const float* block_norm = (const float*)d_in[9];
    float* out = (float*)d_out;

    float* zxb = (float*)d_ws;                               // 32*1024*548 f32
    float* yb  = zxb + (size_t)BB * LL * DINPROJ;            // 32*1024*256 f32

    dim3 g1(9, 1024);
    k1_inproj<<<g1, 256, 0, stream>>>(x, in_proj_w, block_norm, dt_bias, zxb);
    k3_scan<<<128, 256, 0, stream>>>(zxb, conv_w, conv_b, A_log, D, yb);
    k4_out<<<1024, 256, 0, stream>>>(yb, zxb, norm_gate, out_proj_w, x, out);
}

// Round 2
// 304.539 us; speedup vs baseline: 1.8560x; 1.8560x over previous
//
#include <hip/hip_runtime.h>
#include <math.h>

#define BB 32
#define LL 1024
#define DIMM 64
#define DINN 256
#define NHEADS 4
#define DSTATE 16
#define DINPROJ 548
#define EPSF 1e-5f
#define NCH 8     // chunks per sequence
#define CS 128    // chunk size

// ---------------- K1: RMSNorm + in_proj + softplus(dt) ----------------
__global__ __launch_bounds__(256) void k1_inproj(
        const float* __restrict__ x, const float* __restrict__ W,
        const float* __restrict__ bnw, const float* __restrict__ dt_bias,
        float* __restrict__ zxb) {
    __shared__ float u[32][68];
    __shared__ float rstd[32];
    const int t = threadIdx.x;
    const int m0 = blockIdx.y * 32;
    const int ct = blockIdx.x;

    const float* xrow = x + (size_t)m0 * 64;
    #pragma unroll
    for (int i = 0; i < 2; ++i) {
        int idx = t + i * 256;
        float4 v = ((const float4*)xrow)[idx];
        int row = idx >> 4, col4 = (idx & 15) * 4;
        *(float4*)&u[row][col4] = v;
    }
    __syncthreads();
    if (t < 32) {
        float s = 0.f;
        #pragma unroll 8
        for (int k = 0; k < 64; ++k) { float v = u[t][k]; s = fmaf(v, v, s); }
        rstd[t] = rsqrtf(s * (1.f / 64.f) + EPSF);
    }
    __syncthreads();
    #pragma unroll
    for (int i = 0; i < 8; ++i) {
        int idx = t + i * 256; int row = idx >> 6, col = idx & 63;
        u[row][col] *= rstd[row] * bnw[col];
    }
    __syncthreads();

    const int tc = t & 63, tr = t >> 6;
    const int c = ct * 64 + tc;
    const bool valid = (c < DINPROJ);
    const float* wrow = W + (size_t)(valid ? c : 0) * 64;

    float acc[8] = {0.f,0.f,0.f,0.f,0.f,0.f,0.f,0.f};
    for (int kc = 0; kc < 16; ++kc) {
        float4 w4 = *(const float4*)&wrow[kc * 4];
        #pragma unroll
        for (int r = 0; r < 8; ++r) {
            float4 a4 = *(const float4*)&u[tr * 8 + r][kc * 4];
            acc[r] = fmaf(a4.x, w4.x, acc[r]);
            acc[r] = fmaf(a4.y, w4.y, acc[r]);
            acc[r] = fmaf(a4.z, w4.z, acc[r]);
            acc[r] = fmaf(a4.w, w4.w, acc[r]);
        }
    }
    if (valid) {
        float* orow = zxb + (size_t)m0 * DINPROJ + c;
        #pragma unroll
        for (int r = 0; r < 8; ++r) {
            float v = acc[r];
            if (c >= 544) {
                v += dt_bias[c - 544];
                v = fmaxf(v, 0.f) + log1pf(expf(-fabsf(v)));
            }
            orow[(size_t)(tr * 8 + r) * DINPROJ] = v;
        }
    }
}

// ---------------- K3a: conv+SiLU + LOCAL scan per chunk ----------------
// grid 1024 = (b,h,c); block 256: p = t>>2, q = t&3 owns n in [4q,4q+4)
__global__ __launch_bounds__(256) void k3a_scan(
        const float* __restrict__ zxb, const float* __restrict__ conv_w,
        const float* __restrict__ conv_b, const float* __restrict__ A_log,
        const float* __restrict__ Dp, float* __restrict__ y,
        float* __restrict__ h0buf,      // [B][H][8][1024]: slot c+1 <- S_c
        float* __restrict__ cdecbuf,    // [B][H][1024]
        float* __restrict__ Cpost) {    // [B][1024][16]
    const int bid = blockIdx.x;
    const int c = bid & 7, h = (bid >> 3) & 3, b = bid >> 5;
    const int t = threadIdx.x;

    __shared__ float rawx[35][64];
    __shared__ float rawbc[35][32];
    __shared__ float xt[32][64];
    __shared__ float Bt[32][16];
    __shared__ float Ct[32][16];
    __shared__ float dtt[32];
    __shared__ float dAt[32];
    __shared__ float yt[32][64];

    const float A  = -expf(A_log[h]);
    const float Dh = Dp[h];

    const int jx  = t & 63;
    const int cx  = h * 64 + jx;
    const float4 cwx = *(const float4*)&conv_w[cx * 4];
    const float  cbx = conv_b[cx];
    const int jbc = t & 31;
    const int cbc = 256 + jbc;
    const float4 cwb = *(const float4*)&conv_w[cbc * 4];
    const float  cbb = conv_b[cbc];

    const float* zb = zxb + (size_t)b * LL * DINPROJ;
    const int p = t >> 2, q = t & 3, n0 = q * 4;
    float4 st = {0.f, 0.f, 0.f, 0.f};
    float carry = 1.f;                      // lanes t<32 only

    for (int it = 0; it < 4; ++it) {
        const int l0 = c * CS + it * 32;
        for (int i = t; i < 35 * 64; i += 256) {
            int r = i >> 6, j = i & 63;
            int l = l0 - 3 + r;
            rawx[r][j] = (l >= 0) ? zb[(size_t)l * DINPROJ + 256 + h * 64 + j] : 0.f;
        }
        for (int i = t; i < 35 * 32; i += 256) {
            int r = i >> 5, j = i & 31;
            int l = l0 - 3 + r;
            rawbc[r][j] = (l >= 0) ? zb[(size_t)l * DINPROJ + 512 + j] : 0.f;
        }
        if (t < 32) {
            float v = zb[(size_t)(l0 + t) * DINPROJ + 544 + h];
            dtt[t] = v;
            float dA = expf(v * A);
            dAt[t] = dA;
            // inclusive product-scan across 32 lanes
            float run = dA;
            #pragma unroll
            for (int off = 1; off < 32; off <<= 1) {
                float o = __shfl_up(run, off, 32);
                if (t >= off) run *= o;
            }
            cdecbuf[((size_t)(b * 4 + h)) * LL + l0 + t] = carry * run;
            carry *= __shfl(run, 31, 32);
        }
        __syncthreads();
        #pragma unroll
        for (int i = 0; i < 8; ++i) {
            int s = (t + i * 256) >> 6;
            float v = cbx + rawx[s][jx] * cwx.x + rawx[s + 1][jx] * cwx.y
                          + rawx[s + 2][jx] * cwx.z + rawx[s + 3][jx] * cwx.w;
            xt[s][jx] = v / (1.f + expf(-v));
        }
        #pragma unroll
        for (int i = 0; i < 4; ++i) {
            int s = (t + i * 256) >> 5;
            float v = cbb + rawbc[s][jbc] * cwb.x + rawbc[s + 1][jbc] * cwb.y
                          + rawbc[s + 2][jbc] * cwb.z + rawbc[s + 3][jbc] * cwb.w;
            v = v / (1.f + expf(-v));
            if (jbc < 16) Bt[s][jbc] = v;
            else {
                Ct[s][jbc - 16] = v;
                Cpost[((size_t)b * LL + l0 + s) * DSTATE + (jbc - 16)] = v;
            }
        }
        __syncthreads();
        #pragma unroll 4
        for (int s = 0; s < 32; ++s) {
            float xv = xt[s][p];
            float4 Bv = *(const float4*)&Bt[s][n0];
            float4 Cv = *(const float4*)&Ct[s][n0];
            float dt = dtt[s], dA = dAt[s];
            float dtx = dt * xv;
            st.x = fmaf(st.x, dA, dtx * Bv.x);
            st.y = fmaf(st.y, dA, dtx * Bv.y);
            st.z = fmaf(st.z, dA, dtx * Bv.z);
            st.w = fmaf(st.w, dA, dtx * Bv.w);
            float yp = st.x * Cv.x + st.y * Cv.y + st.z * Cv.z + st.w * Cv.w;
            yp += __shfl_xor(yp, 1);
            yp += __shfl_xor(yp, 2);
            if (q == 0) yt[s][p] = fmaf(Dh, xv, yp);
        }
        __syncthreads();
        float* yb = y + ((size_t)b * LL + l0) * DINN + h * 64;
        #pragma unroll
        for (int i = 0; i < 8; ++i) {
            int idx = t + i * 256; int s = idx >> 6, j = idx & 63;
            yb[(size_t)s * DINN + j] = yt[s][j];
        }
        __syncthreads();
    }
    // chunk-end local state -> slot c+1
    if (c < 7) {
        float* Sdst = h0buf + (((size_t)(b * 4 + h)) * 8 + (c + 1)) * 1024 + p * 16 + n0;
        *(float4*)Sdst = st;
    }
}

// ---------------- K3b: chunk-level scan (h0 per chunk) ----------------
// grid 128 = (b,h); thread t owns state elems [4t,4t+4)
__global__ __launch_bounds__(256) void k3b_chunkscan(
        float* __restrict__ h0buf, const float* __restrict__ cdecbuf) {
    const int bh = blockIdx.x;
    const int t = threadIdx.x;
    float* base = h0buf + (size_t)bh * 8 * 1024;
    const float* cd = cdecbuf + (size_t)bh * LL;
    float4 run = {0.f, 0.f, 0.f, 0.f};
    *(float4*)&base[(size_t)t * 4] = run;            // h0[chunk 0] = 0
    #pragma unroll
    for (int c = 1; c < 8; ++c) {
        float P = cd[c * CS - 1];                    // total decay of chunk c-1
        float4 S = *(float4*)&base[(size_t)c * 1024 + t * 4];
        run.x = fmaf(run.x, P, S.x);
        run.y = fmaf(run.y, P, S.y);
        run.z = fmaf(run.z, P, S.z);
        run.w = fmaf(run.w, P, S.w);
        *(float4*)&base[(size_t)c * 1024 + t * 4] = run;
    }
}

// ------- K4: scan-correction + gate + RMSNorm + out_proj + residuals -------
__global__ __launch_bounds__(256) void k4_out(
        const float* __restrict__ y, const float* __restrict__ zxb,
        const float* __restrict__ ngw, const float* __restrict__ Wout,
        const float* __restrict__ x, const float* __restrict__ h0buf,
        const float* __restrict__ cdecbuf, const float* __restrict__ Cpost,
        float* __restrict__ out) {
    __shared__ float g[32][260];
    __shared__ float rstd[32];
    __shared__ float h0s[4][64][16];   // 16 KB
    __shared__ float Cs[32][16];
    __shared__ float cds[32][4];
    const int t = threadIdx.x;
    const int m0 = blockIdx.x * 32;
    const int b  = m0 >> 10;
    const int l0 = m0 & 1023;
    const int ck = l0 >> 7;
    const float* yb = y + (size_t)m0 * DINN;
    const float* zb = zxb + (size_t)m0 * DINPROJ;

    // stage h0 (4 heads), C, cdec
    #pragma unroll
    for (int i = 0; i < 4; ++i) {
        float4 v = *(const float4*)&h0buf[(((size_t)(b * 4 + i)) * 8 + ck) * 1024 + t * 4];
        ((float4*)h0s)[i * 256 + t] = v;
    }
    if (t < 128) {
        int r = t >> 2, n0 = (t & 3) * 4;
        *(float4*)&Cs[r][n0] = *(const float4*)&Cpost[((size_t)b * LL + l0 + r) * DSTATE + n0];
    } else {
        int tt = t - 128;
        int r = tt >> 2, hh = tt & 3;
        cds[r][hh] = cdecbuf[((size_t)(b * 4 + hh)) * LL + l0 + r];
    }
    __syncthreads();

    // register-cache h0 for this thread's 4 channels
    const int ch4 = (t & 63) * 4;          // channel base (constant per thread)
    const int hh  = ch4 >> 6;
    const int p0  = ch4 & 63;
    float4 H[4][4];
    #pragma unroll
    for (int k = 0; k < 4; ++k)
        #pragma unroll
        for (int n4 = 0; n4 < 4; ++n4)
            H[k][n4] = *(const float4*)&h0s[hh][p0 + k][n4 * 4];

    #pragma unroll
    for (int i = 0; i < 8; ++i) {
        int idx = t + i * 256;
        int row = idx >> 6, col4 = (idx & 63) * 4;   // col4 == ch4
        float4 yv = *(const float4*)&yb[(size_t)row * DINN + col4];
        float4 zv = *(const float4*)&zb[(size_t)row * DINPROJ + col4];
        // low-rank scan correction: y += cdec * (C . h0)
        float4 C0 = *(const float4*)&Cs[row][0];
        float4 C1 = *(const float4*)&Cs[row][4];
        float4 C2 = *(const float4*)&Cs[row][8];
        float4 C3 = *(const float4*)&Cs[row][12];
        float cdv = cds[row][hh];
        float corr[4];
        #pragma unroll
        for (int k = 0; k < 4; ++k) {
            float s = H[k][0].x * C0.x + H[k][0].y * C0.y + H[k][0].z * C0.z + H[k][0].w * C0.w;
            s += H[k][1].x * C1.x + H[k][1].y * C1.y + H[k][1].z * C1.z + H[k][1].w * C1.w;
            s += H[k][2].x * C2.x + H[k][2].y * C2.y + H[k][2].z * C2.z + H[k][2].w * C2.w;
            s += H[k][3].x * C3.x + H[k][3].y * C3.y + H[k][3].z * C3.z + H[k][3].w * C3.w;
            corr[k] = s * cdv;
        }
        yv.x += corr[0]; yv.y += corr[1]; yv.z += corr[2]; yv.w += corr[3];
        float4 gv;
        gv.x = yv.x * zv.x / (1.f + expf(-zv.x));
        gv.y = yv.y * zv.y / (1.f + expf(-zv.y));
        gv.z = yv.z * zv.z / (1.f + expf(-zv.z));
        gv.w = yv.w * zv.w / (1.f + expf(-zv.w));
        *(float4*)&g[row][col4] = gv;
    }
    __syncthreads();
    {
        int row = t >> 3, part = t & 7;
        float s = 0.f;
        #pragma unroll 8
        for (int j = 0; j < 32; ++j) { float v = g[row][part * 32 + j]; s = fmaf(v, v, s); }
        s += __shfl_xor(s, 1); s += __shfl_xor(s, 2); s += __shfl_xor(s, 4);
        if (part == 0) rstd[row] = rsqrtf(s * (1.f / 256.f) + EPSF);
    }
    __syncthreads();
    #pragma unroll
    for (int i = 0; i < 8; ++i) {
        int idx = t + i * 256;
        int row = idx >> 6, col4 = (idx & 63) * 4;
        float4 n4 = *(const float4*)&ngw[col4];
        float4 gv = *(const float4*)&g[row][col4];
        float rs = rstd[row];
        gv.x *= rs * n4.x; gv.y *= rs * n4.y; gv.z *= rs * n4.z; gv.w *= rs * n4.w;
        *(float4*)&g[row][col4] = gv;
    }
    __syncthreads();

    const int tc = t & 63, tr = t >> 6;
    const float* wrow = Wout + (size_t)tc * DINN;
    float acc[8] = {0.f,0.f,0.f,0.f,0.f,0.f,0.f,0.f};
    for (int kc = 0; kc < 64; ++kc) {
        float4 w4 = *(const float4*)&wrow[kc * 4];
        #pragma unroll
        for (int r = 0; r < 8; ++r) {
            float4 a4 = *(const float4*)&g[tr * 8 + r][kc * 4];
            acc[r] = fmaf(a4.x, w4.x, acc[r]);
            acc[r] = fmaf(a4.y, w4.y, acc[r]);
            acc[r] = fmaf(a4.z, w4.z, acc[r]);
            acc[r] = fmaf(a4.w, w4.w, acc[r]);
        }
    }
    #pragma unroll
    for (int r = 0; r < 8; ++r) {
        size_t row = (size_t)m0 + tr * 8 + r;
        size_t oidx = row * 64 + tc;
        out[oidx] = acc[r] + 2.f * x[oidx];
    }
}

extern "C" void kernel_launch(void* const* d_in, const int* in_sizes, int n_in,
                              void* d_out, int out_size, void* d_ws, size_t ws_size,
                              hipStream_t stream) {
    const float* x          = (const float*)d_in[0];
    const float* in_proj_w  = (const float*)d_in[1];
    const float* conv_w     = (const float*)d_in[2];
    const float* conv_b     = (const float*)d_in[3];
    const float* dt_bias    = (const float*)d_in[4];
    const float* A_log      = (const float*)d_in[5];
    const float* D          = (const float*)d_in[6];
    const float* norm_gate  = (const float*)d_in[7];
    const float* out_proj_w = (const float*)d_in[8];
    const float* block_norm = (const float*)d_in[9];
    float* out = (float*)d_out;

    float* zxb  = (float*)d_ws;                              // 17,956,864 f32
    float* yb   = zxb + (size_t)BB * LL * DINPROJ;           //  8,388,608 f32
    float* h0b  = yb  + (size_t)BB * LL * DINN;              //  1,048,576 f32
    float* cdec = h0b + (size_t)BB * NHEADS * NCH * 1024;    //    131,072 f32
    float* Cp   = cdec + (size_t)BB * NHEADS * LL;           //    524,288 f32

    dim3 g1(9, 1024);
    k1_inproj<<<g1, 256, 0, stream>>>(x, in_proj_w, block_norm, dt_bias, zxb);
    k3a_scan<<<1024, 256, 0, stream>>>(zxb, conv_w, conv_b, A_log, D, yb, h0b, cdec, Cp);
    k3b_chunkscan<<<128, 256, 0, stream>>>(h0b, cdec);
    k4_out<<<1024, 256, 0, stream>>>(yb, zxb, norm_gate, out_proj_w, x, h0b, cdec, Cp, out);
}

// Round 3
// 132.441 us; speedup vs baseline: 4.2678x; 2.2994x over previous
//
#include <hip/hip_runtime.h>
#include <math.h>

#define BB 32
#define LL 1024
#define DIMM 64
#define DINN 256
#define NHEADS 4
#define DSTATE 16
#define DINPROJ 548
#define EPSF 1e-5f
#define NCH 8     // chunks per sequence
#define CS 128    // chunk size

typedef __attribute__((ext_vector_type(8))) short bf16x8;
typedef __attribute__((ext_vector_type(4))) float f32x4;

__device__ inline ushort f2bf(float f) {
    union { float f; unsigned u; } v; v.f = f;
    unsigned r = (v.u + 0x7FFFu + ((v.u >> 16) & 1u)) >> 16;
    return (ushort)r;
}

// ---------------- K0: convert weights to bf16 ----------------
__global__ __launch_bounds__(256) void kwcvt(
        const float* __restrict__ Win, const float* __restrict__ Wout,
        ushort* __restrict__ Wb, ushort* __restrict__ Wob) {
    int i = blockIdx.x * 256 + threadIdx.x;
    if (i < DINPROJ * 64) Wb[i] = f2bf(Win[i]);
    else if (i < DINPROJ * 64 + 64 * DINN) {
        int j = i - DINPROJ * 64;
        Wob[j] = f2bf(Wout[j]);
    }
}

// ---------------- K1: RMSNorm + in_proj (bf16 MFMA), cols 0..543 ----------------
// grid 1024 (M-tile 32), block 256 = 4 waves; waves split the 34 N-tiles
__global__ __launch_bounds__(256) void k1_mfma(
        const float* __restrict__ x, const ushort* __restrict__ Wb,
        const float* __restrict__ bnw, float* __restrict__ zxb) {
    __shared__ float u[32][68];
    __shared__ float rstd[32];
    const int t = threadIdx.x;
    const int m0 = blockIdx.x * 32;
    const float* xrow = x + (size_t)m0 * 64;
    #pragma unroll
    for (int i = 0; i < 2; ++i) {
        int idx = t + i * 256;
        float4 v = ((const float4*)xrow)[idx];
        *(float4*)&u[idx >> 4][(idx & 15) * 4] = v;
    }
    __syncthreads();
    {
        int row = t >> 3, part = t & 7;
        float s = 0.f;
        #pragma unroll
        for (int j = 0; j < 8; ++j) { float v = u[row][part * 8 + j]; s = fmaf(v, v, s); }
        s += __shfl_xor(s, 1); s += __shfl_xor(s, 2); s += __shfl_xor(s, 4);
        if (part == 0) rstd[row] = rsqrtf(s * (1.f / 64.f) + EPSF);
    }
    __syncthreads();

    const int w = t >> 6, l = t & 63;
    const int a = l & 15, kb = (l >> 4) * 8;

    float4 bw[2][2];
    bw[0][0] = *(const float4*)&bnw[kb];
    bw[0][1] = *(const float4*)&bnw[kb + 4];
    bw[1][0] = *(const float4*)&bnw[32 + kb];
    bw[1][1] = *(const float4*)&bnw[32 + kb + 4];

    bf16x8 af[2][2];
    #pragma unroll
    for (int mt = 0; mt < 2; ++mt) {
        float rs = rstd[mt * 16 + a];
        #pragma unroll
        for (int kk = 0; kk < 2; ++kk) {
            float4 v0 = *(const float4*)&u[mt * 16 + a][kk * 32 + kb];
            float4 v1 = *(const float4*)&u[mt * 16 + a][kk * 32 + kb + 4];
            ushort* p = (ushort*)&af[mt][kk];
            p[0] = f2bf(v0.x * rs * bw[kk][0].x);
            p[1] = f2bf(v0.y * rs * bw[kk][0].y);
            p[2] = f2bf(v0.z * rs * bw[kk][0].z);
            p[3] = f2bf(v0.w * rs * bw[kk][0].w);
            p[4] = f2bf(v1.x * rs * bw[kk][1].x);
            p[5] = f2bf(v1.y * rs * bw[kk][1].y);
            p[6] = f2bf(v1.z * rs * bw[kk][1].z);
            p[7] = f2bf(v1.w * rs * bw[kk][1].w);
        }
    }

    for (int nt = w; nt < 34; nt += 4) {
        const ushort* wbp = Wb + (size_t)(nt * 16 + a) * 64 + kb;
        bf16x8 b0 = *(const bf16x8*)wbp;
        bf16x8 b1 = *(const bf16x8*)(wbp + 32);
        #pragma unroll
        for (int mt = 0; mt < 2; ++mt) {
            f32x4 acc = {0.f, 0.f, 0.f, 0.f};
            acc = __builtin_amdgcn_mfma_f32_16x16x32_bf16(af[mt][0], b0, acc, 0, 0, 0);
            acc = __builtin_amdgcn_mfma_f32_16x16x32_bf16(af[mt][1], b1, acc, 0, 0, 0);
            float* orow = zxb + (size_t)(m0 + mt * 16 + (l >> 4) * 4) * DINPROJ + nt * 16 + a;
            #pragma unroll
            for (int r = 0; r < 4; ++r) orow[(size_t)r * DINPROJ] = acc[r];
        }
    }
}

// ---------------- K1b: dt columns (544..547) in pure fp32 + softplus ----------------
// grid 512 (M-tile 64), block 256
__global__ __launch_bounds__(256) void kdt(
        const float* __restrict__ x, const float* __restrict__ W,
        const float* __restrict__ bnw, const float* __restrict__ dt_bias,
        float* __restrict__ zxb) {
    __shared__ float u[64][68];
    __shared__ float wdt[4][64];
    __shared__ float rstd[64];
    const int t = threadIdx.x;
    const int m0 = blockIdx.x * 64;
    const float* xrow = x + (size_t)m0 * 64;
    #pragma unroll
    for (int i = 0; i < 4; ++i) {
        int idx = t + i * 256;
        float4 v = ((const float4*)xrow)[idx];
        *(float4*)&u[idx >> 4][(idx & 15) * 4] = v;
    }
    wdt[t >> 6][t & 63] = W[(size_t)(544 + (t >> 6)) * 64 + (t & 63)] * bnw[t & 63];
    __syncthreads();
    {
        int row = t >> 2, part = t & 3;
        float s = 0.f;
        #pragma unroll
        for (int j = 0; j < 16; ++j) { float v = u[row][part * 16 + j]; s = fmaf(v, v, s); }
        s += __shfl_xor(s, 1); s += __shfl_xor(s, 2);
        if (part == 0) rstd[row] = rsqrtf(s * (1.f / 64.f) + EPSF);
    }
    __syncthreads();
    const int row = t >> 2, h = t & 3;
    const float* ur = u[row];
    const float* wr = wdt[h];
    float s = 0.f;
    #pragma unroll
    for (int k4 = 0; k4 < 16; ++k4) {
        float4 uv = *(const float4*)&ur[k4 * 4];
        float4 wv = *(const float4*)&wr[k4 * 4];
        s = fmaf(uv.x, wv.x, s); s = fmaf(uv.y, wv.y, s);
        s = fmaf(uv.z, wv.z, s); s = fmaf(uv.w, wv.w, s);
    }
    s = s * rstd[row] + dt_bias[h];
    s = fmaxf(s, 0.f) + log1pf(expf(-fabsf(s)));
    zxb[(size_t)(m0 + row) * DINPROJ + 544 + h] = s;
}

// ---------------- K3a: conv+SiLU + LOCAL scan per chunk ----------------
__global__ __launch_bounds__(256) void k3a_scan(
        const float* __restrict__ zxb, const float* __restrict__ conv_w,
        const float* __restrict__ conv_b, const float* __restrict__ A_log,
        const float* __restrict__ Dp, float* __restrict__ y,
        float* __restrict__ h0buf, float* __restrict__ cdecbuf,
        float* __restrict__ Cpost) {
    const int bid = blockIdx.x;
    const int c = bid & 7, h = (bid >> 3) & 3, b = bid >> 5;
    const int t = threadIdx.x;

    __shared__ float rawx[35][64];
    __shared__ float rawbc[35][32];
    __shared__ float xt[32][64];
    __shared__ float Bt[32][16];
    __shared__ float Ct[32][16];
    __shared__ float dtt[32];
    __shared__ float dAt[32];
    __shared__ float yt[32][64];

    const float A  = -expf(A_log[h]);
    const float Dh = Dp[h];

    const int jx  = t & 63;
    const int cx  = h * 64 + jx;
    const float4 cwx = *(const float4*)&conv_w[cx * 4];
    const float  cbx = conv_b[cx];
    const int jbc = t & 31;
    const int cbc = 256 + jbc;
    const float4 cwb = *(const float4*)&conv_w[cbc * 4];
    const float  cbb = conv_b[cbc];

    const float* zb = zxb + (size_t)b * LL * DINPROJ;
    const int p = t >> 2, q = t & 3, n0 = q * 4;
    float4 st = {0.f, 0.f, 0.f, 0.f};
    float carry = 1.f;

    for (int it = 0; it < 4; ++it) {
        const int l0 = c * CS + it * 32;
        for (int i = t; i < 35 * 64; i += 256) {
            int r = i >> 6, j = i & 63;
            int l = l0 - 3 + r;
            rawx[r][j] = (l >= 0) ? zb[(size_t)l * DINPROJ + 256 + h * 64 + j] : 0.f;
        }
        for (int i = t; i < 35 * 32; i += 256) {
            int r = i >> 5, j = i & 31;
            int l = l0 - 3 + r;
            rawbc[r][j] = (l >= 0) ? zb[(size_t)l * DINPROJ + 512 + j] : 0.f;
        }
        if (t < 32) {
            float v = zb[(size_t)(l0 + t) * DINPROJ + 544 + h];
            dtt[t] = v;
            float dA = expf(v * A);
            dAt[t] = dA;
            float run = dA;
            #pragma unroll
            for (int off = 1; off < 32; off <<= 1) {
                float o = __shfl_up(run, off, 32);
                if (t >= off) run *= o;
            }
            cdecbuf[((size_t)(b * 4 + h)) * LL + l0 + t] = carry * run;
            carry *= __shfl(run, 31, 32);
        }
        __syncthreads();
        #pragma unroll
        for (int i = 0; i < 8; ++i) {
            int s = (t + i * 256) >> 6;
            float v = cbx + rawx[s][jx] * cwx.x + rawx[s + 1][jx] * cwx.y
                          + rawx[s + 2][jx] * cwx.z + rawx[s + 3][jx] * cwx.w;
            xt[s][jx] = v / (1.f + expf(-v));
        }
        #pragma unroll
        for (int i = 0; i < 4; ++i) {
            int s = (t + i * 256) >> 5;
            float v = cbb + rawbc[s][jbc] * cwb.x + rawbc[s + 1][jbc] * cwb.y
                          + rawbc[s + 2][jbc] * cwb.z + rawbc[s + 3][jbc] * cwb.w;
            v = v / (1.f + expf(-v));
            if (jbc < 16) Bt[s][jbc] = v;
            else {
                Ct[s][jbc - 16] = v;
                Cpost[((size_t)b * LL + l0 + s) * DSTATE + (jbc - 16)] = v;
            }
        }
        __syncthreads();
        #pragma unroll 4
        for (int s = 0; s < 32; ++s) {
            float xv = xt[s][p];
            float4 Bv = *(const float4*)&Bt[s][n0];
            float4 Cv = *(const float4*)&Ct[s][n0];
            float dt = dtt[s], dA = dAt[s];
            float dtx = dt * xv;
            st.x = fmaf(st.x, dA, dtx * Bv.x);
            st.y = fmaf(st.y, dA, dtx * Bv.y);
            st.z = fmaf(st.z, dA, dtx * Bv.z);
            st.w = fmaf(st.w, dA, dtx * Bv.w);
            float yp = st.x * Cv.x + st.y * Cv.y + st.z * Cv.z + st.w * Cv.w;
            yp += __shfl_xor(yp, 1);
            yp += __shfl_xor(yp, 2);
            if (q == 0) yt[s][p] = fmaf(Dh, xv, yp);
        }
        __syncthreads();
        float* yb = y + ((size_t)b * LL + l0) * DINN + h * 64;
        #pragma unroll
        for (int i = 0; i < 8; ++i) {
            int idx = t + i * 256; int s = idx >> 6, j = idx & 63;
            yb[(size_t)s * DINN + j] = yt[s][j];
        }
        __syncthreads();
    }
    if (c < 7) {
        float* Sdst = h0buf + (((size_t)(b * 4 + h)) * 8 + (c + 1)) * 1024 + p * 16 + n0;
        *(float4*)Sdst = st;
    }
}

// ---------------- K3b: chunk-level scan ----------------
__global__ __launch_bounds__(256) void k3b_chunkscan(
        float* __restrict__ h0buf, const float* __restrict__ cdecbuf) {
    const int bh = blockIdx.x;
    const int t = threadIdx.x;
    float* base = h0buf + (size_t)bh * 8 * 1024;
    const float* cd = cdecbuf + (size_t)bh * LL;
    float4 run = {0.f, 0.f, 0.f, 0.f};
    *(float4*)&base[(size_t)t * 4] = run;
    #pragma unroll
    for (int c = 1; c < 8; ++c) {
        float P = cd[c * CS - 1];
        float4 S = *(float4*)&base[(size_t)c * 1024 + t * 4];
        run.x = fmaf(run.x, P, S.x);
        run.y = fmaf(run.y, P, S.y);
        run.z = fmaf(run.z, P, S.z);
        run.w = fmaf(run.w, P, S.w);
        *(float4*)&base[(size_t)c * 1024 + t * 4] = run;
    }
}

// ------- K4: correction + gate + RMSNorm + out_proj (bf16 MFMA) + residuals -------
__global__ __launch_bounds__(256) void k4_out(
        const float* __restrict__ y, const float* __restrict__ zxb,
        const float* __restrict__ ngw, const ushort* __restrict__ Wob,
        const float* __restrict__ x, const float* __restrict__ h0buf,
        const float* __restrict__ cdecbuf, const float* __restrict__ Cpost,
        float* __restrict__ out) {
    __shared__ float g[32][264];
    __shared__ float rstd[32];
    __shared__ float Cs[32][16];
    __shared__ float cds[32][4];
    __shared__ union { float h0s[4][64][16]; ushort gb[32][264]; } ua;
    const int t = threadIdx.x;
    const int m0 = blockIdx.x * 32;
    const int b  = m0 >> 10;
    const int l0 = m0 & 1023;
    const int ck = l0 >> 7;
    const float* yb = y + (size_t)m0 * DINN;
    const float* zb = zxb + (size_t)m0 * DINPROJ;

    #pragma unroll
    for (int i = 0; i < 4; ++i) {
        float4 v = *(const float4*)&h0buf[(((size_t)(b * 4 + i)) * 8 + ck) * 1024 + t * 4];
        ((float4*)ua.h0s)[i * 256 + t] = v;
    }
    if (t < 128) {
        int r = t >> 2, n0 = (t & 3) * 4;
        *(float4*)&Cs[r][n0] = *(const float4*)&Cpost[((size_t)b * LL + l0 + r) * DSTATE + n0];
    } else {
        int tt = t - 128;
        int r = tt >> 2, hh = tt & 3;
        cds[r][hh] = cdecbuf[((size_t)(b * 4 + hh)) * LL + l0 + r];
    }
    __syncthreads();

    const int ch4 = (t & 63) * 4;
    const int hh  = ch4 >> 6;
    const int p0  = ch4 & 63;
    float4 H[4][4];
    #pragma unroll
    for (int k = 0; k < 4; ++k)
        #pragma unroll
        for (int n4 = 0; n4 < 4; ++n4)
            H[k][n4] = *(const float4*)&ua.h0s[hh][p0 + k][n4 * 4];

    #pragma unroll
    for (int i = 0; i < 8; ++i) {
        int idx = t + i * 256;
        int row = idx >> 6, col4 = (idx & 63) * 4;
        float4 yv = *(const float4*)&yb[(size_t)row * DINN + col4];
        float4 zv = *(const float4*)&zb[(size_t)row * DINPROJ + col4];
        float4 C0 = *(const float4*)&Cs[row][0];
        float4 C1 = *(const float4*)&Cs[row][4];
        float4 C2 = *(const float4*)&Cs[row][8];
        float4 C3 = *(const float4*)&Cs[row][12];
        float cdv = cds[row][hh];
        float corr[4];
        #pragma unroll
        for (int k = 0; k < 4; ++k) {
            float s = H[k][0].x * C0.x + H[k][0].y * C0.y + H[k][0].z * C0.z + H[k][0].w * C0.w;
            s += H[k][1].x * C1.x + H[k][1].y * C1.y + H[k][1].z * C1.z + H[k][1].w * C1.w;
            s += H[k][2].x * C2.x + H[k][2].y * C2.y + H[k][2].z * C2.z + H[k][2].w * C2.w;
            s += H[k][3].x * C3.x + H[k][3].y * C3.y + H[k][3].z * C3.z + H[k][3].w * C3.w;
            corr[k] = s * cdv;
        }
        yv.x += corr[0]; yv.y += corr[1]; yv.z += corr[2]; yv.w += corr[3];
        float4 gv;
        gv.x = yv.x * zv.x / (1.f + expf(-zv.x));
        gv.y = yv.y * zv.y / (1.f + expf(-zv.y));
        gv.z = yv.z * zv.z / (1.f + expf(-zv.z));
        gv.w = yv.w * zv.w / (1.f + expf(-zv.w));
        *(float4*)&g[row][col4] = gv;
    }
    __syncthreads();
    {
        int row = t >> 3, part = t & 7;
        float s = 0.f;
        #pragma unroll 8
        for (int j = 0; j < 32; ++j) { float v = g[row][part * 32 + j]; s = fmaf(v, v, s); }
        s += __shfl_xor(s, 1); s += __shfl_xor(s, 2); s += __shfl_xor(s, 4);
        if (part == 0) rstd[row] = rsqrtf(s * (1.f / 256.f) + EPSF);
    }
    __syncthreads();
    #pragma unroll
    for (int i = 0; i < 8; ++i) {
        int idx = t + i * 256;
        int row = idx >> 6, col4 = (idx & 63) * 4;
        float4 n4 = *(const float4*)&ngw[col4];
        float4 gv = *(const float4*)&g[row][col4];
        float rs = rstd[row];
        ushort4 o;
        o.x = f2bf(gv.x * rs * n4.x);
        o.y = f2bf(gv.y * rs * n4.y);
        o.z = f2bf(gv.z * rs * n4.z);
        o.w = f2bf(gv.w * rs * n4.w);
        *(ushort4*)&ua.gb[row][col4] = o;
    }
    __syncthreads();

    const int w = t >> 6, l = t & 63;
    const int j = l & 15, kb = (l >> 4) * 8;
    bf16x8 bf[8];
    #pragma unroll
    for (int ks = 0; ks < 8; ++ks)
        bf[ks] = *(const bf16x8*)&Wob[(size_t)(16 * w + j) * DINN + ks * 32 + kb];
    #pragma unroll
    for (int mt = 0; mt < 2; ++mt) {
        f32x4 acc = {0.f, 0.f, 0.f, 0.f};
        #pragma unroll
        for (int ks = 0; ks < 8; ++ks) {
            bf16x8 af = *(const bf16x8*)&ua.gb[mt * 16 + j][ks * 32 + kb];
            acc = __builtin_amdgcn_mfma_f32_16x16x32_bf16(af, bf[ks], acc, 0, 0, 0);
        }
        #pragma unroll
        for (int r = 0; r < 4; ++r) {
            size_t row = (size_t)m0 + mt * 16 + (l >> 4) * 4 + r;
            size_t oidx = row * 64 + 16 * w + j;
            out[oidx] = acc[r] + 2.f * x[oidx];
        }
    }
}

extern "C" void kernel_launch(void* const* d_in, const int* in_sizes, int n_in,
                              void* d_out, int out_size, void* d_ws, size_t ws_size,
                              hipStream_t stream) {
    const float* x          = (const float*)d_in[0];
    const float* in_proj_w  = (const float*)d_in[1];
    const float* conv_w     = (const float*)d_in[2];
    const float* conv_b     = (const float*)d_in[3];
    const float* dt_bias    = (const float*)d_in[4];
    const float* A_log      = (const float*)d_in[5];
    const float* D          = (const float*)d_in[6];
    const float* norm_gate  = (const float*)d_in[7];
    const float* out_proj_w = (const float*)d_in[8];
    const float* block_norm = (const float*)d_in[9];
    float* out = (float*)d_out;

    float* zxb  = (float*)d_ws;
    float* yb   = zxb + (size_t)BB * LL * DINPROJ;
    float* h0b  = yb  + (size_t)BB * LL * DINN;
    float* cdec = h0b + (size_t)BB * NHEADS * NCH * 1024;
    float* Cp   = cdec + (size_t)BB * NHEADS * LL;
    ushort* Wb  = (ushort*)(Cp + (size_t)BB * LL * DSTATE);  // 548*64 bf16
    ushort* Wob = Wb + (size_t)DINPROJ * 64;                 // 64*256 bf16

    kwcvt<<<201, 256, 0, stream>>>(in_proj_w, out_proj_w, Wb, Wob);
    k1_mfma<<<1024, 256, 0, stream>>>(x, Wb, block_norm, zxb);
    kdt<<<512, 256, 0, stream>>>(x, in_proj_w, block_norm, dt_bias, zxb);
    k3a_scan<<<1024, 256, 0, stream>>>(zxb, conv_w, conv_b, A_log, D, yb, h0b, cdec, Cp);
    k3b_chunkscan<<<128, 256, 0, stream>>>(h0b, cdec);
    k4_out<<<1024, 256, 0, stream>>>(yb, zxb, norm_gate, out_proj_w ? Wob : Wob, x, h0b, cdec, Cp, out);
}

// Round 4
// 128.378 us; speedup vs baseline: 4.4029x; 1.0316x over previous
//
#include <hip/hip_runtime.h>
#include <math.h>

#define BB 32
#define LL 1024
#define DIMM 64
#define DINN 256
#define NHEADS 4
#define DSTATE 16
#define DINPROJ 548
#define EPSF 1e-5f
#define NCH 16    // chunks per sequence
#define CS 64     // chunk size

typedef __attribute__((ext_vector_type(8))) short bf16x8;
typedef __attribute__((ext_vector_type(4))) float f32x4;

__device__ inline ushort f2bf(float f) {
    union { float f; unsigned u; } v; v.f = f;
    unsigned r = (v.u + 0x7FFFu + ((v.u >> 16) & 1u)) >> 16;
    return (ushort)r;
}
__device__ inline float bf2f(ushort u) {
    union { float f; unsigned u; } v; v.u = ((unsigned)u) << 16; return v.f;
}

// ---------------- K0: convert weights to bf16 ----------------
__global__ __launch_bounds__(256) void kwcvt(
        const float* __restrict__ Win, const float* __restrict__ Wout,
        ushort* __restrict__ Wb, ushort* __restrict__ Wob) {
    int i = blockIdx.x * 256 + threadIdx.x;
    if (i < DINPROJ * 64) Wb[i] = f2bf(Win[i]);
    else if (i < DINPROJ * 64 + 64 * DINN) {
        int j = i - DINPROJ * 64;
        Wob[j] = f2bf(Wout[j]);
    }
}

// ---------------- K1: RMSNorm + in_proj (bf16 MFMA), cols 0..543 ----------------
__global__ __launch_bounds__(256) void k1_mfma(
        const float* __restrict__ x, const ushort* __restrict__ Wb,
        const float* __restrict__ bnw, float* __restrict__ zxb) {
    __shared__ float u[32][68];
    __shared__ float rstd[32];
    const int t = threadIdx.x;
    const int m0 = blockIdx.x * 32;
    const float* xrow = x + (size_t)m0 * 64;
    #pragma unroll
    for (int i = 0; i < 2; ++i) {
        int idx = t + i * 256;
        float4 v = ((const float4*)xrow)[idx];
        *(float4*)&u[idx >> 4][(idx & 15) * 4] = v;
    }
    __syncthreads();
    {
        int row = t >> 3, part = t & 7;
        float s = 0.f;
        #pragma unroll
        for (int j = 0; j < 8; ++j) { float v = u[row][part * 8 + j]; s = fmaf(v, v, s); }
        s += __shfl_xor(s, 1); s += __shfl_xor(s, 2); s += __shfl_xor(s, 4);
        if (part == 0) rstd[row] = rsqrtf(s * (1.f / 64.f) + EPSF);
    }
    __syncthreads();

    const int w = t >> 6, l = t & 63;
    const int a = l & 15, kb = (l >> 4) * 8;

    float4 bw[2][2];
    bw[0][0] = *(const float4*)&bnw[kb];
    bw[0][1] = *(const float4*)&bnw[kb + 4];
    bw[1][0] = *(const float4*)&bnw[32 + kb];
    bw[1][1] = *(const float4*)&bnw[32 + kb + 4];

    bf16x8 af[2][2];
    #pragma unroll
    for (int mt = 0; mt < 2; ++mt) {
        float rs = rstd[mt * 16 + a];
        #pragma unroll
        for (int kk = 0; kk < 2; ++kk) {
            float4 v0 = *(const float4*)&u[mt * 16 + a][kk * 32 + kb];
            float4 v1 = *(const float4*)&u[mt * 16 + a][kk * 32 + kb + 4];
            ushort* p = (ushort*)&af[mt][kk];
            p[0] = f2bf(v0.x * rs * bw[kk][0].x);
            p[1] = f2bf(v0.y * rs * bw[kk][0].y);
            p[2] = f2bf(v0.z * rs * bw[kk][0].z);
            p[3] = f2bf(v0.w * rs * bw[kk][0].w);
            p[4] = f2bf(v1.x * rs * bw[kk][1].x);
            p[5] = f2bf(v1.y * rs * bw[kk][1].y);
            p[6] = f2bf(v1.z * rs * bw[kk][1].z);
            p[7] = f2bf(v1.w * rs * bw[kk][1].w);
        }
    }

    for (int nt = w; nt < 34; nt += 4) {
        const ushort* wbp = Wb + (size_t)(nt * 16 + a) * 64 + kb;
        bf16x8 b0 = *(const bf16x8*)wbp;
        bf16x8 b1 = *(const bf16x8*)(wbp + 32);
        #pragma unroll
        for (int mt = 0; mt < 2; ++mt) {
            f32x4 acc = {0.f, 0.f, 0.f, 0.f};
            acc = __builtin_amdgcn_mfma_f32_16x16x32_bf16(af[mt][0], b0, acc, 0, 0, 0);
            acc = __builtin_amdgcn_mfma_f32_16x16x32_bf16(af[mt][1], b1, acc, 0, 0, 0);
            float* orow = zxb + (size_t)(m0 + mt * 16 + (l >> 4) * 4) * DINPROJ + nt * 16 + a;
            #pragma unroll
            for (int r = 0; r < 4; ++r) orow[(size_t)r * DINPROJ] = acc[r];
        }
    }
}

// ---------------- K1b: dt columns (544..547) in pure fp32 + softplus ----------------
__global__ __launch_bounds__(256) void kdt(
        const float* __restrict__ x, const float* __restrict__ W,
        const float* __restrict__ bnw, const float* __restrict__ dt_bias,
        float* __restrict__ zxb) {
    __shared__ float u[64][68];
    __shared__ float wdt[4][64];
    __shared__ float rstd[64];
    const int t = threadIdx.x;
    const int m0 = blockIdx.x * 64;
    const float* xrow = x + (size_t)m0 * 64;
    #pragma unroll
    for (int i = 0; i < 4; ++i) {
        int idx = t + i * 256;
        float4 v = ((const float4*)xrow)[idx];
        *(float4*)&u[idx >> 4][(idx & 15) * 4] = v;
    }
    wdt[t >> 6][t & 63] = W[(size_t)(544 + (t >> 6)) * 64 + (t & 63)] * bnw[t & 63];
    __syncthreads();
    {
        int row = t >> 2, part = t & 3;
        float s = 0.f;
        #pragma unroll
        for (int j = 0; j < 16; ++j) { float v = u[row][part * 16 + j]; s = fmaf(v, v, s); }
        s += __shfl_xor(s, 1); s += __shfl_xor(s, 2);
        if (part == 0) rstd[row] = rsqrtf(s * (1.f / 64.f) + EPSF);
    }
    __syncthreads();
    const int row = t >> 2, h = t & 3;
    const float* ur = u[row];
    const float* wr = wdt[h];
    float s = 0.f;
    #pragma unroll
    for (int k4 = 0; k4 < 16; ++k4) {
        float4 uv = *(const float4*)&ur[k4 * 4];
        float4 wv = *(const float4*)&wr[k4 * 4];
        s = fmaf(uv.x, wv.x, s); s = fmaf(uv.y, wv.y, s);
        s = fmaf(uv.z, wv.z, s); s = fmaf(uv.w, wv.w, s);
    }
    s = s * rstd[row] + dt_bias[h];
    s = fmaxf(s, 0.f) + log1pf(expf(-fabsf(s)));
    zxb[(size_t)(m0 + row) * DINPROJ + 544 + h] = s;
}

// ---------------- K3a: SSD chunked scan via MFMA ----------------
// grid 2048 = (b,h,c); block 256 = 4 waves
__global__ __launch_bounds__(256) void k3a_ssd(
        const float* __restrict__ zxb, const float* __restrict__ conv_w,
        const float* __restrict__ conv_b, const float* __restrict__ A_log,
        const float* __restrict__ Dp, float* __restrict__ y,
        float* __restrict__ h0buf, float* __restrict__ cdecbuf,
        float* __restrict__ Cpost) {
    const int bid = blockIdx.x;
    const int c = bid & 15, h = (bid >> 4) & 3, b = bid >> 6;
    const int t = threadIdx.x;

    __shared__ union {
        struct { float rawx[67][64]; float rawbc[67][32]; } st;   // 25.7 KB
        struct { ushort Mb[64][72]; ushort BwT[16][72]; } ssd;    // 11.5 KB
    } uu;
    __shared__ ushort XbT[64][72];   // x transposed [chan][token], bf16
    __shared__ ushort Bb[64][40];    // [token][state(16) pad->40]
    __shared__ ushort Cb[64][40];
    __shared__ float dtt[64], laa[64], ww[64];

    const float A  = -expf(A_log[h]);
    const float Dh = Dp[h];
    const float* zb = zxb + (size_t)b * LL * DINPROJ;
    const int l0 = c * CS;

    // ---- phase 1: stage raw + zero pads + dt/la scan ----
    for (int i = t; i < 67 * 64; i += 256) {
        int r = i >> 6, j = i & 63;
        int l = l0 - 3 + r;
        uu.st.rawx[r][j] = (l >= 0) ? zb[(size_t)l * DINPROJ + 256 + h * 64 + j] : 0.f;
    }
    for (int i = t; i < 67 * 32; i += 256) {
        int r = i >> 5, j = i & 31;
        int l = l0 - 3 + r;
        uu.st.rawbc[r][j] = (l >= 0) ? zb[(size_t)l * DINPROJ + 512 + j] : 0.f;
    }
    {
        uint* pz = (uint*)&Bb[0][0];
        for (int i = t; i < 64 * 40 / 2; i += 256) pz[i] = 0;
        uint* pz2 = (uint*)&Cb[0][0];
        for (int i = t; i < 64 * 40 / 2; i += 256) pz2[i] = 0;
    }
    if (t < 64) {
        float dv = zb[(size_t)(l0 + t) * DINPROJ + 544 + h];  // softplus'ed dt
        float run = dv * A;
        #pragma unroll
        for (int off = 1; off < 64; off <<= 1) {
            float o = __shfl_up(run, off, 64);
            if (t >= off) run += o;
        }
        dtt[t] = dv;
        laa[t] = run;
        cdecbuf[((size_t)(b * 4 + h)) * LL + l0 + t] = expf(run);
        float laEnd = __shfl(run, 63, 64);
        ww[t] = dv * expf(laEnd - run);
    }
    __syncthreads();

    // ---- phase 2: conv + SiLU -> bf16 tiles ----
    {
        const int jx = t & 63;
        const int cx = h * 64 + jx;
        const float4 cwx = *(const float4*)&conv_w[cx * 4];
        const float  cbx = conv_b[cx];
        #pragma unroll
        for (int i = 0; i < 16; ++i) {
            int s = (t >> 6) + i * 4;
            float v = cbx + uu.st.rawx[s][jx] * cwx.x + uu.st.rawx[s + 1][jx] * cwx.y
                          + uu.st.rawx[s + 2][jx] * cwx.z + uu.st.rawx[s + 3][jx] * cwx.w;
            v = v / (1.f + expf(-v));
            XbT[jx][s] = f2bf(v);
        }
        const int jbc = t & 31, cbc = 256 + jbc;
        const float4 cwb = *(const float4*)&conv_w[cbc * 4];
        const float  cbb = conv_b[cbc];
        #pragma unroll
        for (int i = 0; i < 8; ++i) {
            int s = (t >> 5) + i * 8;
            float v = cbb + uu.st.rawbc[s][jbc] * cwb.x + uu.st.rawbc[s + 1][jbc] * cwb.y
                          + uu.st.rawbc[s + 2][jbc] * cwb.z + uu.st.rawbc[s + 3][jbc] * cwb.w;
            v = v / (1.f + expf(-v));
            if (jbc < 16) Bb[s][jbc] = f2bf(v);
            else {
                Cb[s][jbc - 16] = f2bf(v);
                Cpost[((size_t)b * LL + l0 + s) * DSTATE + (jbc - 16)] = v;
            }
        }
    }
    __syncthreads();

    const int w = t >> 6, l = t & 63;
    const int fr = l & 15, fq = l >> 4;

    // ---- phase 3: G = C.B^T (K=32 padded), mask -> Mb; fill BwT ----
    f32x4 gacc[4];
    {
        bf16x8 ca = *(const bf16x8*)&Cb[w * 16 + fr][fq * 8];
        #pragma unroll
        for (int jt = 0; jt < 4; ++jt) {
            bf16x8 bb = *(const bf16x8*)&Bb[jt * 16 + fr][fq * 8];
            f32x4 z = {0.f, 0.f, 0.f, 0.f};
            gacc[jt] = __builtin_amdgcn_mfma_f32_16x16x32_bf16(ca, bb, z, 0, 0, 0);
        }
    }
    #pragma unroll
    for (int jt = 0; jt < 4; ++jt) {
        int j = jt * 16 + fr;
        float laj = laa[j], dtj = dtt[j];
        #pragma unroll
        for (int r = 0; r < 4; ++r) {
            int i = w * 16 + fq * 4 + r;
            float m = (j <= i) ? gacc[jt][r] * expf(laa[i] - laj) * dtj : 0.f;
            uu.ssd.Mb[i][j] = f2bf(m);
        }
    }
    #pragma unroll
    for (int i2 = 0; i2 < 4; ++i2) {
        int idx = t + i2 * 256;
        int n = idx & 15, jj = idx >> 4;
        uu.ssd.BwT[n][jj] = f2bf(ww[jj] * bf2f(Bb[jj][n]));
    }
    __syncthreads();

    // ---- phase 4: Y = M.X (+D skip) and S = X^T.(wB) ----
    {
        bf16x8 ma0 = *(const bf16x8*)&uu.ssd.Mb[w * 16 + fr][fq * 8];
        bf16x8 ma1 = *(const bf16x8*)&uu.ssd.Mb[w * 16 + fr][32 + fq * 8];
        float* ybase = y + ((size_t)b * LL + l0) * DINN + h * 64;
        #pragma unroll
        for (int pt = 0; pt < 4; ++pt) {
            bf16x8 xb0 = *(const bf16x8*)&XbT[pt * 16 + fr][fq * 8];
            bf16x8 xb1 = *(const bf16x8*)&XbT[pt * 16 + fr][32 + fq * 8];
            f32x4 acc = {0.f, 0.f, 0.f, 0.f};
            acc = __builtin_amdgcn_mfma_f32_16x16x32_bf16(ma0, xb0, acc, 0, 0, 0);
            acc = __builtin_amdgcn_mfma_f32_16x16x32_bf16(ma1, xb1, acc, 0, 0, 0);
            #pragma unroll
            for (int r = 0; r < 4; ++r) {
                int i = w * 16 + fq * 4 + r;
                int p = pt * 16 + fr;
                float xv = bf2f(XbT[p][i]);
                ybase[(size_t)i * DINN + p] = acc[r] + Dh * xv;
            }
        }
    }
    if (c < 15) {
        bf16x8 xa0 = *(const bf16x8*)&XbT[w * 16 + fr][fq * 8];
        bf16x8 xa1 = *(const bf16x8*)&XbT[w * 16 + fr][32 + fq * 8];
        bf16x8 bw0 = *(const bf16x8*)&uu.ssd.BwT[fr][fq * 8];
        bf16x8 bw1 = *(const bf16x8*)&uu.ssd.BwT[fr][32 + fq * 8];
        f32x4 acc = {0.f, 0.f, 0.f, 0.f};
        acc = __builtin_amdgcn_mfma_f32_16x16x32_bf16(xa0, bw0, acc, 0, 0, 0);
        acc = __builtin_amdgcn_mfma_f32_16x16x32_bf16(xa1, bw1, acc, 0, 0, 0);
        float* Sdst = h0buf + (((size_t)(b * 4 + h)) * NCH + (c + 1)) * 1024;
        #pragma unroll
        for (int r = 0; r < 4; ++r) {
            int p = w * 16 + fq * 4 + r;
            Sdst[p * 16 + fr] = acc[r];
        }
    }
}

// ---------------- K3b: chunk-level scan (16 chunks) ----------------
__global__ __launch_bounds__(256) void k3b_chunkscan(
        float* __restrict__ h0buf, const float* __restrict__ cdecbuf) {
    const int bh = blockIdx.x;
    const int t = threadIdx.x;
    float* base = h0buf + (size_t)bh * NCH * 1024;
    const float* cd = cdecbuf + (size_t)bh * LL;
    float4 run = {0.f, 0.f, 0.f, 0.f};
    *(float4*)&base[(size_t)t * 4] = run;
    #pragma unroll
    for (int c = 1; c < NCH; ++c) {
        float P = cd[c * CS - 1];
        float4 S = *(float4*)&base[(size_t)c * 1024 + t * 4];
        run.x = fmaf(run.x, P, S.x);
        run.y = fmaf(run.y, P, S.y);
        run.z = fmaf(run.z, P, S.z);
        run.w = fmaf(run.w, P, S.w);
        *(float4*)&base[(size_t)c * 1024 + t * 4] = run;
    }
}

// ------- K4: correction + gate + RMSNorm + out_proj (bf16 MFMA) + residuals -------
__global__ __launch_bounds__(256) void k4_out(
        const float* __restrict__ y, const float* __restrict__ zxb,
        const float* __restrict__ ngw, const ushort* __restrict__ Wob,
        const float* __restrict__ x, const float* __restrict__ h0buf,
        const float* __restrict__ cdecbuf, const float* __restrict__ Cpost,
        float* __restrict__ out) {
    __shared__ float g[32][264];
    __shared__ float rstd[32];
    __shared__ float Cs[32][16];
    __shared__ float cds[32][4];
    __shared__ union { float h0s[4][64][16]; ushort gb[32][264]; } ua;
    const int t = threadIdx.x;
    const int m0 = blockIdx.x * 32;
    const int b  = m0 >> 10;
    const int l0 = m0 & 1023;
    const int ck = l0 >> 6;
    const float* yb = y + (size_t)m0 * DINN;
    const float* zb = zxb + (size_t)m0 * DINPROJ;

    #pragma unroll
    for (int i = 0; i < 4; ++i) {
        float4 v = *(const float4*)&h0buf[(((size_t)(b * 4 + i)) * NCH + ck) * 1024 + t * 4];
        ((float4*)ua.h0s)[i * 256 + t] = v;
    }
    if (t < 128) {
        int r = t >> 2, n0 = (t & 3) * 4;
        *(float4*)&Cs[r][n0] = *(const float4*)&Cpost[((size_t)b * LL + l0 + r) * DSTATE + n0];
    } else {
        int tt = t - 128;
        int r = tt >> 2, hh = tt & 3;
        cds[r][hh] = cdecbuf[((size_t)(b * 4 + hh)) * LL + l0 + r];
    }
    __syncthreads();

    const int ch4 = (t & 63) * 4;
    const int hh  = ch4 >> 6;
    const int p0  = ch4 & 63;
    float4 H[4][4];
    #pragma unroll
    for (int k = 0; k < 4; ++k)
        #pragma unroll
        for (int n4 = 0; n4 < 4; ++n4)
            H[k][n4] = *(const float4*)&ua.h0s[hh][p0 + k][n4 * 4];

    #pragma unroll
    for (int i = 0; i < 8; ++i) {
        int idx = t + i * 256;
        int row = idx >> 6, col4 = (idx & 63) * 4;
        float4 yv = *(const float4*)&yb[(size_t)row * DINN + col4];
        float4 zv = *(const float4*)&zb[(size_t)row * DINPROJ + col4];
        float4 C0 = *(const float4*)&Cs[row][0];
        float4 C1 = *(const float4*)&Cs[row][4];
        float4 C2 = *(const float4*)&Cs[row][8];
        float4 C3 = *(const float4*)&Cs[row][12];
        float cdv = cds[row][hh];
        float corr[4];
        #pragma unroll
        for (int k = 0; k < 4; ++k) {
            float s = H[k][0].x * C0.x + H[k][0].y * C0.y + H[k][0].z * C0.z + H[k][0].w * C0.w;
            s += H[k][1].x * C1.x + H[k][1].y * C1.y + H[k][1].z * C1.z + H[k][1].w * C1.w;
            s += H[k][2].x * C2.x + H[k][2].y * C2.y + H[k][2].z * C2.z + H[k][2].w * C2.w;
            s += H[k][3].x * C3.x + H[k][3].y * C3.y + H[k][3].z * C3.z + H[k][3].w * C3.w;
            corr[k] = s * cdv;
        }
        yv.x += corr[0]; yv.y += corr[1]; yv.z += corr[2]; yv.w += corr[3];
        float4 gv;
        gv.x = yv.x * zv.x / (1.f + expf(-zv.x));
        gv.y = yv.y * zv.y / (1.f + expf(-zv.y));
        gv.z = yv.z * zv.z / (1.f + expf(-zv.z));
        gv.w = yv.w * zv.w / (1.f + expf(-zv.w));
        *(float4*)&g[row][col4] = gv;
    }
    __syncthreads();
    {
        int row = t >> 3, part = t & 7;
        float s = 0.f;
        #pragma unroll 8
        for (int j = 0; j < 32; ++j) { float v = g[row][part * 32 + j]; s = fmaf(v, v, s); }
        s += __shfl_xor(s, 1); s += __shfl_xor(s, 2); s += __shfl_xor(s, 4);
        if (part == 0) rstd[row] = rsqrtf(s * (1.f / 256.f) + EPSF);
    }
    __syncthreads();
    #pragma unroll
    for (int i = 0; i < 8; ++i) {
        int idx = t + i * 256;
        int row = idx >> 6, col4 = (idx & 63) * 4;
        float4 n4 = *(const float4*)&ngw[col4];
        float4 gv = *(const float4*)&g[row][col4];
        float rs = rstd[row];
        ushort4 o;
        o.x = f2bf(gv.x * rs * n4.x);
        o.y = f2bf(gv.y * rs * n4.y);
        o.z = f2bf(gv.z * rs * n4.z);
        o.w = f2bf(gv.w * rs * n4.w);
        *(ushort4*)&ua.gb[row][col4] = o;
    }
    __syncthreads();

    const int w = t >> 6, l = t & 63;
    const int j = l & 15, kb = (l >> 4) * 8;
    bf16x8 bf[8];
    #pragma unroll
    for (int ks = 0; ks < 8; ++ks)
        bf[ks] = *(const bf16x8*)&Wob[(size_t)(16 * w + j) * DINN + ks * 32 + kb];
    #pragma unroll
    for (int mt = 0; mt < 2; ++mt) {
        f32x4 acc = {0.f, 0.f, 0.f, 0.f};
        #pragma unroll
        for (int ks = 0; ks < 8; ++ks) {
            bf16x8 af = *(const bf16x8*)&ua.gb[mt * 16 + j][ks * 32 + kb];
            acc = __builtin_amdgcn_mfma_f32_16x16x32_bf16(af, bf[ks], acc, 0, 0, 0);
        }
        #pragma unroll
        for (int r = 0; r < 4; ++r) {
            size_t row = (size_t)m0 + mt * 16 + (l >> 4) * 4 + r;
            size_t oidx = row * 64 + 16 * w + j;
            out[oidx] = acc[r] + 2.f * x[oidx];
        }
    }
}

extern "C" void kernel_launch(void* const* d_in, const int* in_sizes, int n_in,
                              void* d_out, int out_size, void* d_ws, size_t ws_size,
                              hipStream_t stream) {
    const float* x          = (const float*)d_in[0];
    const float* in_proj_w  = (const float*)d_in[1];
    const float* conv_w     = (const float*)d_in[2];
    const float* conv_b     = (const float*)d_in[3];
    const float* dt_bias    = (const float*)d_in[4];
    const float* A_log      = (const float*)d_in[5];
    const float* D          = (const float*)d_in[6];
    const float* norm_gate  = (const float*)d_in[7];
    const float* out_proj_w = (const float*)d_in[8];
    const float* block_norm = (const float*)d_in[9];
    float* out = (float*)d_out;

    float* zxb  = (float*)d_ws;                               // 17,956,864 f32
    float* yb   = zxb + (size_t)BB * LL * DINPROJ;            //  8,388,608 f32
    float* h0b  = yb  + (size_t)BB * LL * DINN;               //  2,097,152 f32
    float* cdec = h0b + (size_t)BB * NHEADS * NCH * 1024;     //    131,072 f32
    float* Cp   = cdec + (size_t)BB * NHEADS * LL;            //    524,288 f32
    ushort* Wb  = (ushort*)(Cp + (size_t)BB * LL * DSTATE);
    ushort* Wob = Wb + (size_t)DINPROJ * 64;

    kwcvt<<<201, 256, 0, stream>>>(in_proj_w, out_proj_w, Wb, Wob);
    k1_mfma<<<1024, 256, 0, stream>>>(x, Wb, block_norm, zxb);
    kdt<<<512, 256, 0, stream>>>(x, in_proj_w, block_norm, dt_bias, zxb);
    k3a_ssd<<<2048, 256, 0, stream>>>(zxb, conv_w, conv_b, A_log, D, yb, h0b, cdec, Cp);
    k3b_chunkscan<<<128, 256, 0, stream>>>(h0b, cdec);
    k4_out<<<1024, 256, 0, stream>>>(yb, zxb, norm_gate, Wob, x, h0b, cdec, Cp, out);
}

// Round 6
// 112.324 us; speedup vs baseline: 5.0321x; 1.1429x over previous
//
#include <hip/hip_runtime.h>
#include <math.h>

#define BB 32
#define LL 1024
#define DIMM 64
#define DINN 256
#define NHEADS 4
#define DSTATE 16
#define DINPROJ 548
#define EPSF 1e-5f
#define NCH 16    // chunks per sequence
#define CS 64     // chunk size

typedef __attribute__((ext_vector_type(8))) short bf16x8;
typedef __attribute__((ext_vector_type(4))) float f32x4;

__device__ inline ushort f2bf(float f) {
    union { float f; unsigned u; } v; v.f = f;
    unsigned r = (v.u + 0x7FFFu + ((v.u >> 16) & 1u)) >> 16;
    return (ushort)r;
}
__device__ inline float bf2f(ushort u) {
    union { float f; unsigned u; } v; v.u = ((unsigned)u) << 16; return v.f;
}

// ---------------- K0: convert weights to bf16 ----------------
__global__ __launch_bounds__(256) void kwcvt(
        const float* __restrict__ Win, const float* __restrict__ Wout,
        ushort* __restrict__ Wb, ushort* __restrict__ Wob) {
    int i = blockIdx.x * 256 + threadIdx.x;
    if (i < DINPROJ * 64) Wb[i] = f2bf(Win[i]);
    else if (i < DINPROJ * 64 + 64 * DINN) {
        int j = i - DINPROJ * 64;
        Wob[j] = f2bf(Wout[j]);
    }
}

// ------- K1: RMSNorm + in_proj (bf16 MFMA) -> zbuf (bf16) + xbcbuf (bf16) -------
__global__ __launch_bounds__(256) void k1_mfma(
        const float* __restrict__ x, const ushort* __restrict__ Wb,
        const float* __restrict__ bnw, ushort* __restrict__ zbuf,
        ushort* __restrict__ xbcbuf) {
    __shared__ float u[32][68];
    __shared__ float rstd[32];
    const int t = threadIdx.x;
    const int m0 = blockIdx.x * 32;
    const float* xrow = x + (size_t)m0 * 64;
    #pragma unroll
    for (int i = 0; i < 2; ++i) {
        int idx = t + i * 256;
        float4 v = ((const float4*)xrow)[idx];
        *(float4*)&u[idx >> 4][(idx & 15) * 4] = v;
    }
    __syncthreads();
    {
        int row = t >> 3, part = t & 7;
        float s = 0.f;
        #pragma unroll
        for (int j = 0; j < 8; ++j) { float v = u[row][part * 8 + j]; s = fmaf(v, v, s); }
        s += __shfl_xor(s, 1); s += __shfl_xor(s, 2); s += __shfl_xor(s, 4);
        if (part == 0) rstd[row] = rsqrtf(s * (1.f / 64.f) + EPSF);
    }
    __syncthreads();

    const int w = t >> 6, l = t & 63;
    const int a = l & 15, kb = (l >> 4) * 8;

    float4 bw[2][2];
    bw[0][0] = *(const float4*)&bnw[kb];
    bw[0][1] = *(const float4*)&bnw[kb + 4];
    bw[1][0] = *(const float4*)&bnw[32 + kb];
    bw[1][1] = *(const float4*)&bnw[32 + kb + 4];

    bf16x8 af[2][2];
    #pragma unroll
    for (int mt = 0; mt < 2; ++mt) {
        float rs = rstd[mt * 16 + a];
        #pragma unroll
        for (int kk = 0; kk < 2; ++kk) {
            float4 v0 = *(const float4*)&u[mt * 16 + a][kk * 32 + kb];
            float4 v1 = *(const float4*)&u[mt * 16 + a][kk * 32 + kb + 4];
            ushort* p = (ushort*)&af[mt][kk];
            p[0] = f2bf(v0.x * rs * bw[kk][0].x);
            p[1] = f2bf(v0.y * rs * bw[kk][0].y);
            p[2] = f2bf(v0.z * rs * bw[kk][0].z);
            p[3] = f2bf(v0.w * rs * bw[kk][0].w);
            p[4] = f2bf(v1.x * rs * bw[kk][1].x);
            p[5] = f2bf(v1.y * rs * bw[kk][1].y);
            p[6] = f2bf(v1.z * rs * bw[kk][1].z);
            p[7] = f2bf(v1.w * rs * bw[kk][1].w);
        }
    }

    for (int nt = w; nt < 34; nt += 4) {
        const ushort* wbp = Wb + (size_t)(nt * 16 + a) * 64 + kb;
        bf16x8 b0 = *(const bf16x8*)wbp;
        bf16x8 b1 = *(const bf16x8*)(wbp + 32);
        #pragma unroll
        for (int mt = 0; mt < 2; ++mt) {
            f32x4 acc = {0.f, 0.f, 0.f, 0.f};
            acc = __builtin_amdgcn_mfma_f32_16x16x32_bf16(af[mt][0], b0, acc, 0, 0, 0);
            acc = __builtin_amdgcn_mfma_f32_16x16x32_bf16(af[mt][1], b1, acc, 0, 0, 0);
            int row0 = m0 + mt * 16 + (l >> 4) * 4;
            int col = nt * 16 + a;
            if (nt < 16) {
                ushort* orow = zbuf + (size_t)row0 * DINN + col;
                #pragma unroll
                for (int r = 0; r < 4; ++r) orow[(size_t)r * DINN] = f2bf(acc[r]);
            } else {
                ushort* orow = xbcbuf + (size_t)row0 * 288 + (col - 256);
                #pragma unroll
                for (int r = 0; r < 4; ++r) orow[(size_t)r * 288] = f2bf(acc[r]);
            }
        }
    }
}

// ------- K1b: dt columns in pure fp32 + softplus -> dtbuf [B][H][L] -------
__global__ __launch_bounds__(256) void kdt(
        const float* __restrict__ x, const float* __restrict__ W,
        const float* __restrict__ bnw, const float* __restrict__ dt_bias,
        float* __restrict__ dtbuf) {
    __shared__ float u[64][68];
    __shared__ float wdt[4][64];
    __shared__ float rstd[64];
    const int t = threadIdx.x;
    const int m0 = blockIdx.x * 64;
    const float* xrow = x + (size_t)m0 * 64;
    #pragma unroll
    for (int i = 0; i < 4; ++i) {
        int idx = t + i * 256;
        float4 v = ((const float4*)xrow)[idx];
        *(float4*)&u[idx >> 4][(idx & 15) * 4] = v;
    }
    wdt[t >> 6][t & 63] = W[(size_t)(544 + (t >> 6)) * 64 + (t & 63)] * bnw[t & 63];
    __syncthreads();
    {
        int row = t >> 2, part = t & 3;
        float s = 0.f;
        #pragma unroll
        for (int j = 0; j < 16; ++j) { float v = u[row][part * 16 + j]; s = fmaf(v, v, s); }
        s += __shfl_xor(s, 1); s += __shfl_xor(s, 2);
        if (part == 0) rstd[row] = rsqrtf(s * (1.f / 64.f) + EPSF);
    }
    __syncthreads();
    const int row = t >> 2, h = t & 3;
    const int b = m0 >> 10, lofs = (m0 & 1023) + row;
    const float* ur = u[row];
    const float* wr = wdt[h];
    float s = 0.f;
    #pragma unroll
    for (int k4 = 0; k4 < 16; ++k4) {
        float4 uv = *(const float4*)&ur[k4 * 4];
        float4 wv = *(const float4*)&wr[k4 * 4];
        s = fmaf(uv.x, wv.x, s); s = fmaf(uv.y, wv.y, s);
        s = fmaf(uv.z, wv.z, s); s = fmaf(uv.w, wv.w, s);
    }
    s = s * rstd[row] + dt_bias[h];
    s = fmaxf(s, 0.f) + log1pf(expf(-fabsf(s)));
    dtbuf[((size_t)(b * 4 + h)) * LL + lofs] = s;
}

// ---------------- K3a: SSD chunked scan via MFMA (bf16 inputs) ----------------
// grid 2048 = (b,h,c); block 256 = 4 waves
__global__ __launch_bounds__(256) void k3a_ssd(
        const ushort* __restrict__ xbcbuf, const float* __restrict__ dtbuf,
        const float* __restrict__ conv_w, const float* __restrict__ conv_b,
        const float* __restrict__ A_log, const float* __restrict__ Dp,
        float* __restrict__ y, float* __restrict__ h0buf,
        float* __restrict__ cdecbuf, float* __restrict__ Cpost) {
    const int bid = blockIdx.x;
    const int c = bid & 15, h = (bid >> 4) & 3, b = bid >> 6;
    const int t = threadIdx.x;

    __shared__ union {
        struct { ushort rawx[67][64]; ushort rawbc[67][32]; } st;  // 12.9 KB
        struct { ushort Mb[64][72]; ushort BwT[16][72]; } ssd;     // 11.5 KB
    } uu;
    __shared__ ushort XbT[64][72];   // x transposed [chan][token], bf16
    __shared__ ushort Bb[64][40];    // [token][state(16) pad->40]
    __shared__ ushort Cb[64][40];
    __shared__ float dtt[64], laa[64], ww[64];

    const float A  = -expf(A_log[h]);
    const float Dh = Dp[h];
    const int l0 = c * CS;
    const ushort* xb = xbcbuf + (size_t)b * LL * 288;   // per-batch base

    // ---- phase 1: stage raw (bf16) + zero pads + dt/la scan ----
    for (int i = t; i < 67 * 32; i += 256) {
        int r = i >> 5, cu = i & 31;
        int l = l0 - 3 + r;
        ((uint*)&uu.st.rawx[r][0])[cu] =
            (l >= 0) ? ((const uint*)(xb + (size_t)l * 288 + h * 64))[cu] : 0u;
    }
    for (int i = t; i < 67 * 16; i += 256) {
        int r = i >> 4, cu = i & 15;
        int l = l0 - 3 + r;
        ((uint*)&uu.st.rawbc[r][0])[cu] =
            (l >= 0) ? ((const uint*)(xb + (size_t)l * 288 + 256))[cu] : 0u;
    }
    {
        uint* pz = (uint*)&Bb[0][0];
        for (int i = t; i < 64 * 40 / 2; i += 256) pz[i] = 0;
        uint* pz2 = (uint*)&Cb[0][0];
        for (int i = t; i < 64 * 40 / 2; i += 256) pz2[i] = 0;
    }
    if (t < 64) {
        float dv = dtbuf[((size_t)(b * 4 + h)) * LL + l0 + t];  // softplus'ed dt
        float run = dv * A;
        #pragma unroll
        for (int off = 1; off < 64; off <<= 1) {
            float o = __shfl_up(run, off, 64);
            if (t >= off) run += o;
        }
        dtt[t] = dv;
        laa[t] = run;
        cdecbuf[((size_t)(b * 4 + h)) * LL + l0 + t] = expf(run);
        float laEnd = __shfl(run, 63, 64);
        ww[t] = dv * expf(laEnd - run);
    }
    __syncthreads();

    // ---- phase 2: conv + SiLU -> bf16 tiles ----
    {
        const int jx = t & 63;
        const int cx = h * 64 + jx;
        const float4 cwx = *(const float4*)&conv_w[cx * 4];
        const float  cbx = conv_b[cx];
        #pragma unroll
        for (int i = 0; i < 16; ++i) {
            int s = (t >> 6) + i * 4;
            float v = cbx + bf2f(uu.st.rawx[s][jx]) * cwx.x
                          + bf2f(uu.st.rawx[s + 1][jx]) * cwx.y
                          + bf2f(uu.st.rawx[s + 2][jx]) * cwx.z
                          + bf2f(uu.st.rawx[s + 3][jx]) * cwx.w;
            v = v / (1.f + expf(-v));
            XbT[jx][s] = f2bf(v);
        }
        const int jbc = t & 31, cbc = 256 + jbc;
        const float4 cwb = *(const float4*)&conv_w[cbc * 4];
        const float  cbb = conv_b[cbc];
        #pragma unroll
        for (int i = 0; i < 8; ++i) {
            int s = (t >> 5) + i * 8;
            float v = cbb + bf2f(uu.st.rawbc[s][jbc]) * cwb.x
                          + bf2f(uu.st.rawbc[s + 1][jbc]) * cwb.y
                          + bf2f(uu.st.rawbc[s + 2][jbc]) * cwb.z
                          + bf2f(uu.st.rawbc[s + 3][jbc]) * cwb.w;
            v = v / (1.f + expf(-v));
            if (jbc < 16) Bb[s][jbc] = f2bf(v);
            else {
                Cb[s][jbc - 16] = f2bf(v);
                Cpost[((size_t)b * LL + l0 + s) * DSTATE + (jbc - 16)] = v;
            }
        }
    }
    __syncthreads();

    const int w = t >> 6, l = t & 63;
    const int fr = l & 15, fq = l >> 4;

    // ---- phase 3: G = C.B^T (K=32 padded), mask -> Mb; fill BwT ----
    f32x4 gacc[4];
    {
        bf16x8 ca = *(const bf16x8*)&Cb[w * 16 + fr][fq * 8];
        #pragma unroll
        for (int jt = 0; jt < 4; ++jt) {
            bf16x8 bb = *(const bf16x8*)&Bb[jt * 16 + fr][fq * 8];
            f32x4 z = {0.f, 0.f, 0.f, 0.f};
            gacc[jt] = __builtin_amdgcn_mfma_f32_16x16x32_bf16(ca, bb, z, 0, 0, 0);
        }
    }
    #pragma unroll
    for (int jt = 0; jt < 4; ++jt) {
        int j = jt * 16 + fr;
        float laj = laa[j], dtj = dtt[j];
        #pragma unroll
        for (int r = 0; r < 4; ++r) {
            int i = w * 16 + fq * 4 + r;
            float m = (j <= i) ? gacc[jt][r] * expf(laa[i] - laj) * dtj : 0.f;
            uu.ssd.Mb[i][j] = f2bf(m);
        }
    }
    #pragma unroll
    for (int i2 = 0; i2 < 4; ++i2) {
        int idx = t + i2 * 256;
        int n = idx & 15, jj = idx >> 4;
        uu.ssd.BwT[n][jj] = f2bf(ww[jj] * bf2f(Bb[jj][n]));
    }
    __syncthreads();

    // ---- phase 4: Y = M.X (+D skip) and S = X^T.(wB) ----
    {
        bf16x8 ma0 = *(const bf16x8*)&uu.ssd.Mb[w * 16 + fr][fq * 8];
        bf16x8 ma1 = *(const bf16x8*)&uu.ssd.Mb[w * 16 + fr][32 + fq * 8];
        float* ybase = y + ((size_t)b * LL + l0) * DINN + h * 64;
        #pragma unroll
        for (int pt = 0; pt < 4; ++pt) {
            bf16x8 xb0 = *(const bf16x8*)&XbT[pt * 16 + fr][fq * 8];
            bf16x8 xb1 = *(const bf16x8*)&XbT[pt * 16 + fr][32 + fq * 8];
            f32x4 acc = {0.f, 0.f, 0.f, 0.f};
            acc = __builtin_amdgcn_mfma_f32_16x16x32_bf16(ma0, xb0, acc, 0, 0, 0);
            acc = __builtin_amdgcn_mfma_f32_16x16x32_bf16(ma1, xb1, acc, 0, 0, 0);
            #pragma unroll
            for (int r = 0; r < 4; ++r) {
                int i = w * 16 + fq * 4 + r;
                int p = pt * 16 + fr;
                float xv = bf2f(XbT[p][i]);
                ybase[(size_t)i * DINN + p] = acc[r] + Dh * xv;
            }
        }
    }
    if (c < 15) {
        bf16x8 xa0 = *(const bf16x8*)&XbT[w * 16 + fr][fq * 8];
        bf16x8 xa1 = *(const bf16x8*)&XbT[w * 16 + fr][32 + fq * 8];
        bf16x8 bw0 = *(const bf16x8*)&uu.ssd.BwT[fr][fq * 8];
        bf16x8 bw1 = *(const bf16x8*)&uu.ssd.BwT[fr][32 + fq * 8];
        f32x4 acc = {0.f, 0.f, 0.f, 0.f};
        acc = __builtin_amdgcn_mfma_f32_16x16x32_bf16(xa0, bw0, acc, 0, 0, 0);
        acc = __builtin_amdgcn_mfma_f32_16x16x32_bf16(xa1, bw1, acc, 0, 0, 0);
        float* Sdst = h0buf + (((size_t)(b * 4 + h)) * NCH + (c + 1)) * 1024;
        #pragma unroll
        for (int r = 0; r < 4; ++r) {
            int p = w * 16 + fq * 4 + r;
            Sdst[p * 16 + fr] = acc[r];
        }
    }
}

// ---------------- K3b: chunk-level scan (16 chunks) ----------------
__global__ __launch_bounds__(256) void k3b_chunkscan(
        float* __restrict__ h0buf, const float* __restrict__ cdecbuf) {
    const int bh = blockIdx.x;
    const int t = threadIdx.x;
    float* base = h0buf + (size_t)bh * NCH * 1024;
    const float* cd = cdecbuf + (size_t)bh * LL;
    float4 run = {0.f, 0.f, 0.f, 0.f};
    *(float4*)&base[(size_t)t * 4] = run;
    #pragma unroll
    for (int c = 1; c < NCH; ++c) {
        float P = cd[c * CS - 1];
        float4 S = *(float4*)&base[(size_t)c * 1024 + t * 4];
        run.x = fmaf(run.x, P, S.x);
        run.y = fmaf(run.y, P, S.y);
        run.z = fmaf(run.z, P, S.z);
        run.w = fmaf(run.w, P, S.w);
        *(float4*)&base[(size_t)c * 1024 + t * 4] = run;
    }
}

// ------- K4: correction + gate + RMSNorm + out_proj (bf16 MFMA) + residuals -------
__global__ __launch_bounds__(256) void k4_out(
        const float* __restrict__ y, const ushort* __restrict__ zbuf,
        const float* __restrict__ ngw, const ushort* __restrict__ Wob,
        const float* __restrict__ x, const float* __restrict__ h0buf,
        const float* __restrict__ cdecbuf, const float* __restrict__ Cpost,
        float* __restrict__ out) {
    __shared__ float g[32][264];
    __shared__ float rstd[32];
    __shared__ float Cs[32][16];
    __shared__ float cds[32][4];
    __shared__ union { float h0s[4][64][16]; ushort gb[32][264]; } ua;
    const int t = threadIdx.x;
    const int m0 = blockIdx.x * 32;
    const int b  = m0 >> 10;
    const int l0 = m0 & 1023;
    const int ck = l0 >> 6;
    const float* yb = y + (size_t)m0 * DINN;
    const ushort* zb = zbuf + (size_t)m0 * DINN;

    #pragma unroll
    for (int i = 0; i < 4; ++i) {
        float4 v = *(const float4*)&h0buf[(((size_t)(b * 4 + i)) * NCH + ck) * 1024 + t * 4];
        ((float4*)ua.h0s)[i * 256 + t] = v;
    }
    if (t < 128) {
        int r = t >> 2, n0 = (t & 3) * 4;
        *(float4*)&Cs[r][n0] = *(const float4*)&Cpost[((size_t)b * LL + l0 + r) * DSTATE + n0];
    } else {
        int tt = t - 128;
        int r = tt >> 2, hh = tt & 3;
        cds[r][hh] = cdecbuf[((size_t)(b * 4 + hh)) * LL + l0 + r];
    }
    __syncthreads();

    const int ch4 = (t & 63) * 4;
    const int hh  = ch4 >> 6;
    const int p0  = ch4 & 63;
    float4 H[4][4];
    #pragma unroll
    for (int k = 0; k < 4; ++k)
        #pragma unroll
        for (int n4 = 0; n4 < 4; ++n4)
            H[k][n4] = *(const float4*)&ua.h0s[hh][p0 + k][n4 * 4];

    #pragma unroll
    for (int i = 0; i < 8; ++i) {
        int idx = t + i * 256;
        int row = idx >> 6, col4 = (idx & 63) * 4;
        float4 yv = *(const float4*)&yb[(size_t)row * DINN + col4];
        ushort4 zu = *(const ushort4*)&zb[(size_t)row * DINN + col4];
        float4 zv = { bf2f(zu.x), bf2f(zu.y), bf2f(zu.z), bf2f(zu.w) };
        float4 C0 = *(const float4*)&Cs[row][0];
        float4 C1 = *(const float4*)&Cs[row][4];
        float4 C2 = *(const float4*)&Cs[row][8];
        float4 C3 = *(const float4*)&Cs[row][12];
        float cdv = cds[row][hh];
        float corr[4];
        #pragma unroll
        for (int k = 0; k < 4; ++k) {
            float s = H[k][0].x * C0.x + H[k][0].y * C0.y + H[k][0].z * C0.z + H[k][0].w * C0.w;
            s += H[k][1].x * C1.x + H[k][1].y * C1.y + H[k][1].z * C1.z + H[k][1].w * C1.w;
            s += H[k][2].x * C2.x + H[k][2].y * C2.y + H[k][2].z * C2.z + H[k][2].w * C2.w;
            s += H[k][3].x * C3.x + H[k][3].y * C3.y + H[k][3].z * C3.z + H[k][3].w * C3.w;
            corr[k] = s * cdv;
        }
        yv.x += corr[0]; yv.y += corr[1]; yv.z += corr[2]; yv.w += corr[3];
        float4 gv;
        gv.x = yv.x * zv.x / (1.f + expf(-zv.x));
        gv.y = yv.y * zv.y / (1.f + expf(-zv.y));
        gv.z = yv.z * zv.z / (1.f + expf(-zv.z));
        gv.w = yv.w * zv.w / (1.f + expf(-zv.w));
        *(float4*)&g[row][col4] = gv;
    }
    __syncthreads();
    {
        int row = t >> 3, part = t & 7;
        float s = 0.f;
        #pragma unroll 8
        for (int j = 0; j < 32; ++j) { float v = g[row][part * 32 + j]; s = fmaf(v, v, s); }
        s += __shfl_xor(s, 1); s += __shfl_xor(s, 2); s += __shfl_xor(s, 4);
        if (part == 0) rstd[row] = rsqrtf(s * (1.f / 256.f) + EPSF);
    }
    __syncthreads();
    #pragma unroll
    for (int i = 0; i < 8; ++i) {
        int idx = t + i * 256;
        int row = idx >> 6, col4 = (idx & 63) * 4;
        float4 n4 = *(const float4*)&ngw[col4];
        float4 gv = *(const float4*)&g[row][col4];
        float rs = rstd[row];
        ushort4 o;
        o.x = f2bf(gv.x * rs * n4.x);
        o.y = f2bf(gv.y * rs * n4.y);
        o.z = f2bf(gv.z * rs * n4.z);
        o.w = f2bf(gv.w * rs * n4.w);
        *(ushort4*)&ua.gb[row][col4] = o;
    }
    __syncthreads();

    const int w = t >> 6, l = t & 63;
    const int j = l & 15, kb = (l >> 4) * 8;
    bf16x8 bf[8];
    #pragma unroll
    for (int ks = 0; ks < 8; ++ks)
        bf[ks] = *(const bf16x8*)&Wob[(size_t)(16 * w + j) * DINN + ks * 32 + kb];
    #pragma unroll
    for (int mt = 0; mt < 2; ++mt) {
        f32x4 acc = {0.f, 0.f, 0.f, 0.f};
        #pragma unroll
        for (int ks = 0; ks < 8; ++ks) {
            bf16x8 af = *(const bf16x8*)&ua.gb[mt * 16 + j][ks * 32 + kb];
            acc = __builtin_amdgcn_mfma_f32_16x16x32_bf16(af, bf[ks], acc, 0, 0, 0);
        }
        #pragma unroll
        for (int r = 0; r < 4; ++r) {
            size_t row = (size_t)m0 + mt * 16 + (l >> 4) * 4 + r;
            size_t oidx = row * 64 + 16 * w + j;
            out[oidx] = acc[r] + 2.f * x[oidx];
        }
    }
}

extern "C" void kernel_launch(void* const* d_in, const int* in_sizes, int n_in,
                              void* d_out, int out_size, void* d_ws, size_t ws_size,
                              hipStream_t stream) {
    const float* x          = (const float*)d_in[0];
    const float* in_proj_w  = (const float*)d_in[1];
    const float* conv_w     = (const float*)d_in[2];
    const float* conv_b     = (const float*)d_in[3];
    const float* dt_bias    = (const float*)d_in[4];
    const float* A_log      = (const float*)d_in[5];
    const float* D          = (const float*)d_in[6];
    const float* norm_gate  = (const float*)d_in[7];
    const float* out_proj_w = (const float*)d_in[8];
    const float* block_norm = (const float*)d_in[9];
    float* out = (float*)d_out;

    float* yb    = (float*)d_ws;                               //  8,388,608 f32
    float* h0b   = yb   + (size_t)BB * LL * DINN;              //  2,097,152 f32
    float* cdec  = h0b  + (size_t)BB * NHEADS * NCH * 1024;    //    131,072 f32
    float* Cp    = cdec + (size_t)BB * NHEADS * LL;            //    524,288 f32
    float* dtb   = Cp   + (size_t)BB * LL * DSTATE;            //    131,072 f32
    ushort* zbuf = (ushort*)(dtb + (size_t)BB * NHEADS * LL);  //  8,388,608 us
    ushort* xbc  = zbuf + (size_t)BB * LL * DINN;              //  9,437,184 us
    ushort* Wb   = xbc  + (size_t)BB * LL * 288;               //     35,072 us
    ushort* Wob  = Wb   + (size_t)DINPROJ * 64;                //     16,384 us

    kwcvt<<<201, 256, 0, stream>>>(in_proj_w, out_proj_w, Wb, Wob);
    k1_mfma<<<1024, 256, 0, stream>>>(x, Wb, block_norm, zbuf, xbc);
    kdt<<<512, 256, 0, stream>>>(x, in_proj_w, block_norm, dt_bias, dtb);
    k3a_ssd<<<2048, 256, 0, stream>>>(xbc, dtb, conv_w, conv_b, A_log, D, yb, h0b, cdec, Cp);
    k3b_chunkscan<<<128, 256, 0, stream>>>(h0b, cdec);
    k4_out<<<1024, 256, 0, stream>>>(yb, zbuf, norm_gate, Wob, x, h0b, cdec, Cp, out);
}